// Round 1
// baseline (460.873 us; speedup 1.0000x reference)
//
#include <hip/hip_runtime.h>
#include <hip/hip_bf16.h>

// Problem constants
#define TT   512
#define BB   32
#define TS_F 76
#define N_WF 200
#define WF_LEN 1000
#define TEXT_D 200
#define WF_D 100
#define HID  256
#define FC_H 256
#define NCLS 2
#define ROWS (TT*BB)          // 16384
#define FEAT_K (TEXT_D+HID+WF_D) // 556

// ---------------- generic tiled fp32 GEMM ----------------
// C[b] = act(scale * (A[b] @ B[b]) + bias), row-major, batched via blockIdx.z
#define BM 64
#define BN 64
#define BK 16

__global__ __launch_bounds__(256)
void gemm_f32(const float* __restrict__ A, int lda, long long sAb,
              const float* __restrict__ Bm, int ldb, long long sBb,
              const float* __restrict__ bias,
              float* __restrict__ C, int ldc, long long sCb,
              int M, int N, int K, float scale, int act)
{
    const int bz = blockIdx.z;
    A  += (long long)bz * sAb;
    Bm += (long long)bz * sBb;
    C  += (long long)bz * sCb;

    __shared__ float As[BK][BM + 4];
    __shared__ float Bs[BK][BN];

    const int tid = threadIdx.x;
    const int row0 = blockIdx.y * BM;
    const int col0 = blockIdx.x * BN;
    const int ty = tid >> 4, tx = tid & 15;

    float acc[4][4] = {};

    for (int k0 = 0; k0 < K; k0 += BK) {
        // A tile 64x16
        #pragma unroll
        for (int e = tid; e < BM * BK; e += 256) {
            int i = e >> 4, j = e & 15;
            int r = row0 + i, k = k0 + j;
            As[j][i] = (r < M && k < K) ? A[(long long)r * lda + k] : 0.f;
        }
        // B tile 16x64
        #pragma unroll
        for (int e = tid; e < BK * BN; e += 256) {
            int j = e >> 6, c = e & 63;
            int kk = k0 + j, cc = col0 + c;
            Bs[j][c] = (kk < K && cc < N) ? Bm[(long long)kk * ldb + cc] : 0.f;
        }
        __syncthreads();
        #pragma unroll
        for (int j = 0; j < BK; j++) {
            float a[4], b[4];
            #pragma unroll
            for (int q = 0; q < 4; q++) a[q] = As[j][ty * 4 + q];
            #pragma unroll
            for (int q = 0; q < 4; q++) b[q] = Bs[j][tx * 4 + q];
            #pragma unroll
            for (int i = 0; i < 4; i++)
                #pragma unroll
                for (int q = 0; q < 4; q++) acc[i][q] += a[i] * b[q];
        }
        __syncthreads();
    }

    #pragma unroll
    for (int i = 0; i < 4; i++) {
        int r = row0 + ty * 4 + i;
        if (r >= M) continue;
        #pragma unroll
        for (int q = 0; q < 4; q++) {
            int c = col0 + tx * 4 + q;
            if (c >= N) continue;
            float v = acc[i][q] * scale;
            if (bias) v += bias[c];
            if (act == 1) v = tanhf(v);
            else if (act == 2) v = fmaxf(v, 0.f);
            C[(long long)r * ldc + c] = v;
        }
    }
}

// ---------------- fused feat-gather GEMM: h = relu(feat @ W1 + b1) ----------
// feat[r][k] = k<200 ? texts[r*200+k] : k<456 ? ts_out[r*256+k-200]
//                                             : spread[r*100+k-456]
__global__ __launch_bounds__(256)
void gemm_feat_w1(const float* __restrict__ texts,
                  const float* __restrict__ ts_out,
                  const float* __restrict__ spread,
                  const float* __restrict__ W1,   // 556 x 256
                  const float* __restrict__ b1,
                  float* __restrict__ H)          // 16384 x 256
{
    __shared__ float As[BK][BM + 4];
    __shared__ float Bs[BK][BN];

    const int tid = threadIdx.x;
    const int row0 = blockIdx.y * BM;
    const int col0 = blockIdx.x * BN;
    const int ty = tid >> 4, tx = tid & 15;

    float acc[4][4] = {};

    for (int k0 = 0; k0 < FEAT_K; k0 += BK) {
        #pragma unroll
        for (int e = tid; e < BM * BK; e += 256) {
            int i = e >> 4, j = e & 15;
            int r = row0 + i, k = k0 + j;
            float v = 0.f;
            if (k < FEAT_K) {
                if (k < TEXT_D)            v = texts[r * TEXT_D + k];
                else if (k < TEXT_D + HID) v = ts_out[r * HID + (k - TEXT_D)];
                else                       v = spread[r * WF_D + (k - TEXT_D - HID)];
            }
            As[j][i] = v;
        }
        #pragma unroll
        for (int e = tid; e < BK * BN; e += 256) {
            int j = e >> 6, c = e & 63;
            int kk = k0 + j;
            Bs[j][c] = (kk < FEAT_K) ? W1[kk * FC_H + col0 + c] : 0.f;
        }
        __syncthreads();
        #pragma unroll
        for (int j = 0; j < BK; j++) {
            float a[4], b[4];
            #pragma unroll
            for (int q = 0; q < 4; q++) a[q] = As[j][ty * 4 + q];
            #pragma unroll
            for (int q = 0; q < 4; q++) b[q] = Bs[j][tx * 4 + q];
            #pragma unroll
            for (int i = 0; i < 4; i++)
                #pragma unroll
                for (int q = 0; q < 4; q++) acc[i][q] += a[i] * b[q];
        }
        __syncthreads();
    }

    #pragma unroll
    for (int i = 0; i < 4; i++) {
        int r = row0 + ty * 4 + i;
        #pragma unroll
        for (int q = 0; q < 4; q++) {
            int c = col0 + tx * 4 + q;
            float v = acc[i][q] + b1[c];
            H[(long long)r * FC_H + c] = fmaxf(v, 0.f);
        }
    }
}

// ---------------- head: out = h @ W2 + b2 (K=256, N=2), one wave per row ----
__global__ __launch_bounds__(256)
void head_kernel(const float* __restrict__ H, const float* __restrict__ W2,
                 const float* __restrict__ b2, float* __restrict__ out)
{
    const int wave = threadIdx.x >> 6;
    const int lane = threadIdx.x & 63;
    const int r = blockIdx.x * 4 + wave;
    if (r >= ROWS) return;

    const float4 hv = ((const float4*)(H + (long long)r * FC_H))[lane];
    float o0 = 0.f, o1 = 0.f;
    #pragma unroll
    for (int q = 0; q < 4; q++) {
        int k = lane * 4 + q;
        float hk = (&hv.x)[q];
        o0 += hk * W2[k * 2 + 0];
        o1 += hk * W2[k * 2 + 1];
    }
    #pragma unroll
    for (int off = 32; off > 0; off >>= 1) {
        o0 += __shfl_down(o0, off);
        o1 += __shfl_down(o1, off);
    }
    if (lane == 0) {
        out[r * 2 + 0] = o0 + b2[0];
        out[r * 2 + 1] = o1 + b2[1];
    }
}

extern "C" void kernel_launch(void* const* d_in, const int* in_sizes, int n_in,
                              void* d_out, int out_size, void* d_ws, size_t ws_size,
                              hipStream_t stream)
{
    const float* texts = (const float*)d_in[0];   // (512,32,200)
    const float* ts    = (const float*)d_in[1];   // (512,32,76)
    const float* wf    = (const float*)d_in[2];   // (32,200,1000)
    const float* wwm   = (const float*)d_in[3];   // (32,512,200)
    const float* W_wf  = (const float*)d_in[4];   // (1000,100)
    const float* b_wf  = (const float*)d_in[5];
    const float* W_ts  = (const float*)d_in[6];   // (76,256)
    const float* b_ts  = (const float*)d_in[7];
    const float* W1    = (const float*)d_in[8];   // (556,256)
    const float* b1    = (const float*)d_in[9];
    const float* W2    = (const float*)d_in[10];  // (256,2)
    const float* b2    = (const float*)d_in[11];
    float* out = (float*)d_out;

    float* ws      = (float*)d_ws;
    float* wf_out  = ws;                                   // 32*200*100   = 640000
    float* ts_out  = wf_out + BB * N_WF * WF_D;            // 16384*256    = 4194304
    float* spread  = ts_out + ROWS * HID;                  // 32*512*100   = 1638400
    float* h       = spread + BB * TT * WF_D;              // 16384*256    = 4194304

    dim3 blk(256);

    // 1) wf_out = waveform @ W_wf + b_wf   (M=6400, N=100, K=1000)
    {
        dim3 grid((WF_D + BN - 1) / BN, (BB * N_WF + BM - 1) / BM, 1);
        gemm_f32<<<grid, blk, 0, stream>>>(wf, WF_LEN, 0, W_wf, WF_D, 0, b_wf,
                                           wf_out, WF_D, 0,
                                           BB * N_WF, WF_D, WF_LEN, 1.0f, 0);
    }
    // 2) ts_out = tanh(ts @ W_ts + b_ts)   (M=16384, N=256, K=76)
    {
        dim3 grid((HID + BN - 1) / BN, (ROWS + BM - 1) / BM, 1);
        gemm_f32<<<grid, blk, 0, stream>>>(ts, TS_F, 0, W_ts, HID, 0, b_ts,
                                           ts_out, HID, 0,
                                           ROWS, HID, TS_F, 1.0f, 1);
    }
    // 3) spread[b] = (wwm[b] @ wf_out[b]) / 200  (32 x [512,100,200])
    {
        dim3 grid((WF_D + BN - 1) / BN, (TT + BM - 1) / BM, BB);
        gemm_f32<<<grid, blk, 0, stream>>>(wwm, N_WF, (long long)TT * N_WF,
                                           wf_out, WF_D, (long long)N_WF * WF_D,
                                           nullptr,
                                           spread, WF_D, (long long)TT * WF_D,
                                           TT, WF_D, N_WF, 1.0f / N_WF, 0);
    }
    // 4) h = relu(feat @ W1 + b1)  (M=16384, N=256, K=556) with fused gather
    {
        dim3 grid(FC_H / BN, ROWS / BM, 1);
        gemm_feat_w1<<<grid, blk, 0, stream>>>(texts, ts_out, spread, W1, b1, h);
    }
    // 5) out = h @ W2 + b2
    {
        dim3 grid(ROWS / 4);
        head_kernel<<<grid, blk, 0, stream>>>(h, W2, b2, out);
    }
}

// Round 2
// 273.055 us; speedup vs baseline: 1.6878x; 1.6878x over previous
//
#include <hip/hip_runtime.h>
#include <hip/hip_bf16.h>

// Problem constants
#define TT   512
#define BB   32
#define TS_F 76
#define N_WF 200
#define WF_LEN 1000
#define TEXT_D 200
#define WF_D 100
#define HID  256
#define FC_H 256
#define NCLS 2
#define ROWS (TT*BB)              // 16384
#define FEAT_K (TEXT_D+HID+WF_D)  // 556
#define FEAT_KP 576               // padded to 32

typedef __attribute__((ext_vector_type(8))) short short8;
typedef __attribute__((ext_vector_type(4))) float f32x4;

// Round-to-nearest-even bf16 split: v ~= hi + lo with ~fp32 combined precision
__device__ __forceinline__ void split_bf16(float v, short& h, short& l) {
    unsigned u = __builtin_bit_cast(unsigned, v);
    unsigned hr = (u + 0x7FFFu + ((u >> 16) & 1u)) & 0xFFFF0000u;
    h = (short)(hr >> 16);
    float r = v - __builtin_bit_cast(float, hr);
    unsigned u2 = __builtin_bit_cast(unsigned, r);
    unsigned lr = (u2 + 0x7FFFu + ((u2 >> 16) & 1u)) & 0xFFFF0000u;
    l = (short)(lr >> 16);
}

// ---------------- generic tiled fp32 GEMM with optional split-K ------------
// If kps>0: blockIdx.z selects K-chunk [z*kps, min(K,(z+1)*kps)), C += z*sCb
// Else: blockIdx.z is batch index with strides sAb/sBb/sCb.
#define BM 64
#define BN 64
#define BK 16

__global__ __launch_bounds__(256)
void gemm_f32(const float* __restrict__ A, int lda, long long sAb,
              const float* __restrict__ Bm, int ldb, long long sBb,
              const float* __restrict__ bias,
              float* __restrict__ C, int ldc, long long sCb,
              int M, int N, int K, float scale, int act, int kps)
{
    const int bz = blockIdx.z;
    A  += (long long)bz * sAb;
    Bm += (long long)bz * sBb;
    C  += (long long)bz * sCb;

    int kb = kps > 0 ? bz * kps : 0;
    int ke = kps > 0 ? min(K, kb + kps) : K;

    __shared__ float As[BK][BM + 4];
    __shared__ float Bs[BK][BN];

    const int tid = threadIdx.x;
    const int row0 = blockIdx.y * BM;
    const int col0 = blockIdx.x * BN;
    const int ty = tid >> 4, tx = tid & 15;

    float acc[4][4] = {};

    for (int k0 = kb; k0 < ke; k0 += BK) {
        #pragma unroll
        for (int e = tid; e < BM * BK; e += 256) {
            int i = e >> 4, j = e & 15;
            int r = row0 + i, k = k0 + j;
            As[j][i] = (r < M && k < ke) ? A[(long long)r * lda + k] : 0.f;
        }
        #pragma unroll
        for (int e = tid; e < BK * BN; e += 256) {
            int j = e >> 6, c = e & 63;
            int kk = k0 + j, cc = col0 + c;
            Bs[j][c] = (kk < ke && cc < N) ? Bm[(long long)kk * ldb + cc] : 0.f;
        }
        __syncthreads();
        #pragma unroll
        for (int j = 0; j < BK; j++) {
            float a[4], b[4];
            #pragma unroll
            for (int q = 0; q < 4; q++) a[q] = As[j][ty * 4 + q];
            #pragma unroll
            for (int q = 0; q < 4; q++) b[q] = Bs[j][tx * 4 + q];
            #pragma unroll
            for (int i = 0; i < 4; i++)
                #pragma unroll
                for (int q = 0; q < 4; q++) acc[i][q] += a[i] * b[q];
        }
        __syncthreads();
    }

    #pragma unroll
    for (int i = 0; i < 4; i++) {
        int r = row0 + ty * 4 + i;
        if (r >= M) continue;
        #pragma unroll
        for (int q = 0; q < 4; q++) {
            int c = col0 + tx * 4 + q;
            if (c >= N) continue;
            float v = acc[i][q] * scale;
            if (bias) v += bias[c];
            if (act == 1) v = tanhf(v);
            else if (act == 2) v = fmaxf(v, 0.f);
            C[(long long)r * ldc + c] = v;
        }
    }
}

// --------- stage-1 split-K reduce: wf_out = sum_z part[z] + b_wf -----------
#define S1_KS 8
__global__ __launch_bounds__(256)
void reduce_s1(const float* __restrict__ part, const float* __restrict__ b_wf,
               float* __restrict__ wf_out)
{
    int idx = blockIdx.x * 256 + threadIdx.x;
    if (idx >= BB * N_WF * WF_D) return;
    int c = idx % WF_D;
    float s = b_wf[c];
    #pragma unroll
    for (int z = 0; z < S1_KS; z++) s += part[(long long)z * (BB*N_WF*WF_D) + idx];
    wf_out[idx] = s;
}

// --------- one-time prep: W1 -> transposed bf16 hi/lo [n=256][k=576] -------
__global__ __launch_bounds__(256)
void prep_w1t(const float* __restrict__ W1, short* __restrict__ w1th,
              short* __restrict__ w1tl)
{
    int idx = blockIdx.x * 256 + threadIdx.x;   // 72 blocks * 256 = 18432
    int n = idx / 72;              // 0..255
    int kc = (idx % 72) * 8;       // 0..568
    #pragma unroll
    for (int j = 0; j < 8; j++) {
        int k = kc + j;
        float v = (k < FEAT_K) ? W1[k * FC_H + n] : 0.f;
        short h, l;
        split_bf16(v, h, l);
        w1th[n * FEAT_KP + k] = h;
        w1tl[n * FEAT_KP + k] = l;
    }
}

// --------- stage 4: h = relu(feat @ W1 + b1) via compensated bf16 MFMA -----
// feat gathered from texts / ts_out / spread (fp32) -> split bf16 hi/lo in LDS
#define S4_BM 128
#define S4_BN 64
#define S4_KP 40    // LDS k-stride (elements): 80B rows -> 16B-aligned, ~2-way banks

__global__ __launch_bounds__(256)
void gemm_feat_w1_mfma(const float* __restrict__ texts,
                       const float* __restrict__ ts_out,
                       const float* __restrict__ spread,
                       const short* __restrict__ w1th,   // [256][576]
                       const short* __restrict__ w1tl,
                       const float* __restrict__ b1,
                       float* __restrict__ H)
{
    __shared__ short Ah[S4_BM][S4_KP];
    __shared__ short Al[S4_BM][S4_KP];
    __shared__ short Bh[S4_BN][S4_KP];
    __shared__ short Bl[S4_BN][S4_KP];

    const int tid  = threadIdx.x;
    const int wv   = tid >> 6;
    const int lane = tid & 63;
    const int row0 = blockIdx.y * S4_BM;
    const int col0 = blockIdx.x * S4_BN;

    const int m16 = lane & 15;
    const int kq  = (lane >> 4) * 8;

    f32x4 acc[2][4];
    #pragma unroll
    for (int i = 0; i < 2; i++)
        #pragma unroll
        for (int j = 0; j < 4; j++) acc[i][j] = f32x4{0.f, 0.f, 0.f, 0.f};

    const int ar  = tid >> 1;          // 0..127 (A row)
    const int akh = (tid & 1) * 16;    // 0/16  (A k-half)
    const int bc  = tid >> 2;          // 0..63  (B col)
    const int bkh = (tid & 3) * 8;     // 0..24  (B k-quarter)
    const long long gr = row0 + ar;

    for (int k0 = 0; k0 < FEAT_KP; k0 += 32) {
        __syncthreads();
        // ---- stage A (gathered feat row, 16 k's per thread) ----
        {
            int kc = k0 + akh;
            float v[16];
            const float* p = nullptr;
            if (kc + 16 <= TEXT_D)
                p = texts + gr * TEXT_D + kc;
            else if (kc >= TEXT_D && kc + 16 <= TEXT_D + HID)
                p = ts_out + gr * HID + (kc - TEXT_D);
            else if (kc >= TEXT_D + HID && kc + 16 <= FEAT_K)
                p = spread + gr * WF_D + (kc - TEXT_D - HID);
            if (p) {
                #pragma unroll
                for (int q = 0; q < 4; q++) {
                    float4 t4 = ((const float4*)p)[q];
                    v[4*q+0] = t4.x; v[4*q+1] = t4.y; v[4*q+2] = t4.z; v[4*q+3] = t4.w;
                }
            } else {
                #pragma unroll
                for (int j = 0; j < 16; j++) {
                    int k = kc + j;
                    float x = 0.f;
                    if (k < TEXT_D)            x = texts[gr * TEXT_D + k];
                    else if (k < TEXT_D + HID) x = ts_out[gr * HID + (k - TEXT_D)];
                    else if (k < FEAT_K)       x = spread[gr * WF_D + (k - TEXT_D - HID)];
                    v[j] = x;
                }
            }
            short8 h0, h1, l0, l1;
            #pragma unroll
            for (int j = 0; j < 8; j++) {
                short h, l;
                split_bf16(v[j], h, l);     h0[j] = h; l0[j] = l;
                split_bf16(v[j+8], h, l);   h1[j] = h; l1[j] = l;
            }
            *(short8*)&Ah[ar][akh]     = h0;
            *(short8*)&Ah[ar][akh + 8] = h1;
            *(short8*)&Al[ar][akh]     = l0;
            *(short8*)&Al[ar][akh + 8] = l1;
        }
        // ---- stage B (pre-split transposed W1) ----
        {
            long long off = (long long)(col0 + bc) * FEAT_KP + k0 + bkh;
            *(short8*)&Bh[bc][bkh] = *(const short8*)(w1th + off);
            *(short8*)&Bl[bc][bkh] = *(const short8*)(w1tl + off);
        }
        __syncthreads();

        // ---- fragments + MFMA ----
        short8 a_h[2], a_l[2], b_h[4], b_l[4];
        #pragma unroll
        for (int i = 0; i < 2; i++) {
            a_h[i] = *(const short8*)&Ah[wv*32 + i*16 + m16][kq];
            a_l[i] = *(const short8*)&Al[wv*32 + i*16 + m16][kq];
        }
        #pragma unroll
        for (int j = 0; j < 4; j++) {
            b_h[j] = *(const short8*)&Bh[j*16 + m16][kq];
            b_l[j] = *(const short8*)&Bl[j*16 + m16][kq];
        }
        #pragma unroll
        for (int i = 0; i < 2; i++)
            #pragma unroll
            for (int j = 0; j < 4; j++) {
                acc[i][j] = __builtin_amdgcn_mfma_f32_16x16x32_bf16(a_h[i], b_h[j], acc[i][j], 0, 0, 0);
                acc[i][j] = __builtin_amdgcn_mfma_f32_16x16x32_bf16(a_h[i], b_l[j], acc[i][j], 0, 0, 0);
                acc[i][j] = __builtin_amdgcn_mfma_f32_16x16x32_bf16(a_l[i], b_h[j], acc[i][j], 0, 0, 0);
            }
    }

    // ---- epilogue: bias + relu, C/D layout col=lane&15, row=(lane>>4)*4+r ----
    #pragma unroll
    for (int i = 0; i < 2; i++) {
        #pragma unroll
        for (int j = 0; j < 4; j++) {
            int r0 = row0 + wv*32 + i*16 + (lane >> 4) * 4;
            int c  = col0 + j*16 + m16;
            float bv = b1[c];
            #pragma unroll
            for (int r = 0; r < 4; r++) {
                float v = acc[i][j][r] + bv;
                H[(long long)(r0 + r) * FC_H + c] = fmaxf(v, 0.f);
            }
        }
    }
}

// ---------------- head: out = h @ W2 + b2 (K=256, N=2) ---------------------
__global__ __launch_bounds__(256)
void head_kernel(const float* __restrict__ H, const float* __restrict__ W2,
                 const float* __restrict__ b2, float* __restrict__ out)
{
    const int wave = threadIdx.x >> 6;
    const int lane = threadIdx.x & 63;
    const int r = blockIdx.x * 4 + wave;
    if (r >= ROWS) return;

    const float4 hv = ((const float4*)(H + (long long)r * FC_H))[lane];
    float o0 = 0.f, o1 = 0.f;
    #pragma unroll
    for (int q = 0; q < 4; q++) {
        int k = lane * 4 + q;
        float hk = (&hv.x)[q];
        o0 += hk * W2[k * 2 + 0];
        o1 += hk * W2[k * 2 + 1];
    }
    #pragma unroll
    for (int off = 32; off > 0; off >>= 1) {
        o0 += __shfl_down(o0, off);
        o1 += __shfl_down(o1, off);
    }
    if (lane == 0) {
        out[r * 2 + 0] = o0 + b2[0];
        out[r * 2 + 1] = o1 + b2[1];
    }
}

extern "C" void kernel_launch(void* const* d_in, const int* in_sizes, int n_in,
                              void* d_out, int out_size, void* d_ws, size_t ws_size,
                              hipStream_t stream)
{
    const float* texts = (const float*)d_in[0];   // (512,32,200)
    const float* ts    = (const float*)d_in[1];   // (512,32,76)
    const float* wf    = (const float*)d_in[2];   // (32,200,1000)
    const float* wwm   = (const float*)d_in[3];   // (32,512,200)
    const float* W_wf  = (const float*)d_in[4];   // (1000,100)
    const float* b_wf  = (const float*)d_in[5];
    const float* W_ts  = (const float*)d_in[6];   // (76,256)
    const float* b_ts  = (const float*)d_in[7];
    const float* W1    = (const float*)d_in[8];   // (556,256)
    const float* b1    = (const float*)d_in[9];
    const float* W2    = (const float*)d_in[10];  // (256,2)
    const float* b2    = (const float*)d_in[11];
    float* out = (float*)d_out;

    // workspace layout
    short* w1th = (short*)d_ws;                       // 256*576
    short* w1tl = w1th + FC_H * FEAT_KP;              // 256*576
    float* fbase = (float*)(w1tl + FC_H * FEAT_KP);   // 1,179,648 B offset (16B aligned)
    float* wf_out = fbase;                            // 640,000
    float* ts_out = wf_out + BB * N_WF * WF_D;        // 4,194,304
    float* spread = ts_out + (long long)ROWS * HID;   // 1,638,400
    float* h      = spread + BB * TT * WF_D;          // 4,194,304
    // split-K partials (5,120,000 floats) alias spread+h (5,832,704) — dead
    // before stage 3 writes spread.
    float* part   = spread;

    dim3 blk(256);

    // 0) one-time W1 transpose/split
    prep_w1t<<<72, blk, 0, stream>>>(W1, w1th, w1tl);

    // 1) stage-1 GEMM, split-K: part[z] = wf @ W_wf over k-chunk z
    {
        dim3 grid((WF_D + BN - 1) / BN, (BB * N_WF + BM - 1) / BM, S1_KS);
        gemm_f32<<<grid, blk, 0, stream>>>(wf, WF_LEN, 0, W_wf, WF_D, 0, nullptr,
                                           part, WF_D, (long long)BB * N_WF * WF_D,
                                           BB * N_WF, WF_D, WF_LEN, 1.0f, 0,
                                           WF_LEN / S1_KS);
        reduce_s1<<<(BB * N_WF * WF_D + 255) / 256, blk, 0, stream>>>(part, b_wf, wf_out);
    }
    // 2) ts_out = tanh(ts @ W_ts + b_ts)
    {
        dim3 grid(HID / BN, ROWS / BM, 1);
        gemm_f32<<<grid, blk, 0, stream>>>(ts, TS_F, 0, W_ts, HID, 0, b_ts,
                                           ts_out, HID, 0,
                                           ROWS, HID, TS_F, 1.0f, 1, 0);
    }
    // 3) spread[b] = (wwm[b] @ wf_out[b]) / 200
    {
        dim3 grid((WF_D + BN - 1) / BN, TT / BM, BB);
        gemm_f32<<<grid, blk, 0, stream>>>(wwm, N_WF, (long long)TT * N_WF,
                                           wf_out, WF_D, (long long)N_WF * WF_D,
                                           nullptr,
                                           spread, WF_D, (long long)TT * WF_D,
                                           TT, WF_D, N_WF, 1.0f / N_WF, 0, 0);
    }
    // 4) h = relu(feat @ W1 + b1) — compensated bf16 MFMA, fused gather
    {
        dim3 grid(FC_H / S4_BN, ROWS / S4_BM, 1);
        gemm_feat_w1_mfma<<<grid, blk, 0, stream>>>(texts, ts_out, spread,
                                                    w1th, w1tl, b1, h);
    }
    // 5) out = h @ W2 + b2
    head_kernel<<<ROWS / 4, blk, 0, stream>>>(h, W2, b2, out);
}

// Round 3
// 213.506 us; speedup vs baseline: 2.1586x; 1.2789x over previous
//
#include <hip/hip_runtime.h>
#include <hip/hip_bf16.h>

// Problem constants
#define TT   512
#define BB   32
#define TS_F 76
#define N_WF 200
#define WF_LEN 1000
#define TEXT_D 200
#define WF_D 100
#define HID  256
#define FC_H 256
#define NCLS 2
#define ROWS (TT*BB)              // 16384
#define FEAT_K 556
#define FEAT_KP 576

// stage-1 geometry
#define S1_KPAD 1024
#define S1_NPAD 128
#define S1_Z    4
#define S1_KPS  256
#define S1T_LD  224               // padded n_wf dim of transposed wf_out
#define S2_KPAD 96
#define S3_KPAD 224

typedef __attribute__((ext_vector_type(8))) short short8;
typedef __attribute__((ext_vector_type(4))) float f32x4;

// RNE bf16 split: v ~= hi + lo (~fp32 combined precision)
__device__ __forceinline__ void split_bf16(float v, short& h, short& l) {
    unsigned u = __builtin_bit_cast(unsigned, v);
    unsigned hr = (u + 0x7FFFu + ((u >> 16) & 1u)) & 0xFFFF0000u;
    h = (short)(hr >> 16);
    float r = v - __builtin_bit_cast(float, hr);
    unsigned u2 = __builtin_bit_cast(unsigned, r);
    unsigned lr = (u2 + 0x7FFFu + ((u2 >> 16) & 1u)) & 0xFFFF0000u;
    l = (short)(lr >> 16);
}

// =====================================================================
// Unified compensated-bf16 MFMA GEMM. Tile: 64 rows x (CT*16) cols x 32 k.
// A: fp32 row-major [m][k] (split hi/lo on the fly).
// B: pre-split bf16 hi/lo, transposed [n][ldbk] (k padded, zero-filled).
// emode 1: v = tanh(acc + bias[c]); split -> feat[(frow0+r)][fcol+c]   (c<N)
// emode 2: v = acc*scale;           split -> feat[(frow0+r)][fcol+c]   (c<N)
// emode 3: split-K transposed partial (s1): C[(b*128+c)*224 + n] = v (0 if c>=N)
// kps>0: blockIdx.z = K chunk [z*kps, z*kps+kps), C += z*sCb
// kps=0: blockIdx.z = batch  (A += z*sAb, B += z*sBb, frow0 = z*fRowStride)
// =====================================================================
template <int CT>
__global__ __launch_bounds__(256)
void gemm_comp(const float* __restrict__ A, int lda, long long sAb,
               const short* __restrict__ BhG, const short* __restrict__ BlG,
               int ldbk, long long sBb,
               const float* __restrict__ bias, float scale,
               float* __restrict__ C, long long sCb,
               short* __restrict__ fH, short* __restrict__ fL,
               int fcol, int fRowStride,
               int N, int K, int kps, int emode)
{
    constexpr int BN = CT * 16;
    __shared__ short Ah[64][40], Al[64][40];
    __shared__ short Bh[BN][40], Bl[BN][40];

    const int tid  = threadIdx.x;
    const int wv   = tid >> 6, lane = tid & 63;
    const int m16  = lane & 15, quad = lane >> 4;
    const int kq   = quad * 8;
    const int row0 = blockIdx.y * 64;
    const int col0 = blockIdx.x * BN;
    const int bz   = blockIdx.z;

    int kb = 0, kend;
    long long frow0 = 0;
    const float* Ab  = A;
    const short* Bhb = BhG;
    const short* Blb = BlG;
    float* Cb = C;
    if (kps > 0) {
        kb = bz * kps; kend = kb + kps;
        Cb = C + (long long)bz * sCb;
    } else {
        Ab  = A + (long long)bz * sAb;
        Bhb = BhG + (long long)bz * sBb;
        Blb = BlG + (long long)bz * sBb;
        frow0 = (long long)bz * fRowStride;
        kend = ((K + 31) >> 5) << 5;
    }

    f32x4 acc[CT];
    #pragma unroll
    for (int j = 0; j < CT; j++) acc[j] = f32x4{0.f, 0.f, 0.f, 0.f};

    const int ar = tid >> 2, akc = (tid & 3) * 8;

    for (int k0 = kb; k0 < kend; k0 += 32) {
        __syncthreads();
        // ---- A stage (64 x 32 fp32 -> split) ----
        {
            int kk = k0 + akc;
            const float* ap = Ab + (long long)(row0 + ar) * lda + kk;
            float v[8];
            if (kk + 8 <= K) {
                float4 t0 = ((const float4*)ap)[0];
                float4 t1 = ((const float4*)ap)[1];
                v[0]=t0.x; v[1]=t0.y; v[2]=t0.z; v[3]=t0.w;
                v[4]=t1.x; v[5]=t1.y; v[6]=t1.z; v[7]=t1.w;
            } else {
                #pragma unroll
                for (int q = 0; q < 8; q++) v[q] = (kk + q < K) ? ap[q] : 0.f;
            }
            short8 h8, l8;
            #pragma unroll
            for (int q = 0; q < 8; q++) { short h, l; split_bf16(v[q], h, l); h8[q]=h; l8[q]=l; }
            *(short8*)&Ah[ar][akc] = h8;
            *(short8*)&Al[ar][akc] = l8;
        }
        // ---- B stage (BN x 32, pre-split) ----
        if constexpr (CT == 4) {
            int bc = tid >> 2, bkc = (tid & 3) * 8;
            long long off = (long long)(col0 + bc) * ldbk + k0 + bkc;
            *(short8*)&Bh[bc][bkc] = *(const short8*)(Bhb + off);
            *(short8*)&Bl[bc][bkc] = *(const short8*)(Blb + off);
        } else {
            int bc = tid >> 1, bkc = (tid & 1) * 16;
            long long off = (long long)(col0 + bc) * ldbk + k0 + bkc;
            *(short8*)&Bh[bc][bkc]     = *(const short8*)(Bhb + off);
            *(short8*)&Bh[bc][bkc + 8] = *(const short8*)(Bhb + off + 8);
            *(short8*)&Bl[bc][bkc]     = *(const short8*)(Blb + off);
            *(short8*)&Bl[bc][bkc + 8] = *(const short8*)(Blb + off + 8);
        }
        __syncthreads();

        short8 a_h = *(const short8*)&Ah[wv * 16 + m16][kq];
        short8 a_l = *(const short8*)&Al[wv * 16 + m16][kq];
        #pragma unroll
        for (int j = 0; j < CT; j++) {
            short8 b_h = *(const short8*)&Bh[j * 16 + m16][kq];
            short8 b_l = *(const short8*)&Bl[j * 16 + m16][kq];
            acc[j] = __builtin_amdgcn_mfma_f32_16x16x32_bf16(a_h, b_h, acc[j], 0, 0, 0);
            acc[j] = __builtin_amdgcn_mfma_f32_16x16x32_bf16(a_h, b_l, acc[j], 0, 0, 0);
            acc[j] = __builtin_amdgcn_mfma_f32_16x16x32_bf16(a_l, b_h, acc[j], 0, 0, 0);
        }
    }

    // ---- epilogue: C/D layout col = lane&15 (+j*16), row = quad*4 + rr ----
    #pragma unroll
    for (int j = 0; j < CT; j++) {
        int c = col0 + j * 16 + m16;
        #pragma unroll
        for (int rr = 0; rr < 4; rr++) {
            int r = row0 + wv * 16 + quad * 4 + rr;
            float v = acc[j][rr] * scale;
            if (emode == 3) {
                int b = r / N_WF, n = r - b * N_WF;
                Cb[((long long)(b * S1_NPAD + c)) * S1T_LD + n] = (c < N) ? v : 0.f;
            } else if (c < N) {
                if (bias) v += bias[c];
                if (emode == 1) v = tanhf(v);
                short h, l; split_bf16(v, h, l);
                long long fo = (frow0 + r) * (long long)FEAT_KP + fcol + c;
                fH[fo] = h; fL[fo] = l;
            }
        }
    }
}

// ---- s1 reduce: wf_outT hi/lo [b][128][224] = sum_z partT + b_wf ----------
__global__ __launch_bounds__(256)
void reduce_s1_T(const float* __restrict__ part, const float* __restrict__ b_wf,
                 short* __restrict__ oh, short* __restrict__ ol)
{
    int idx = blockIdx.x * 256 + threadIdx.x;      // exact: 917504 = 3584*256
    int rem = idx % (S1_NPAD * S1T_LD);
    int d = rem / S1T_LD, n = rem % S1T_LD;
    float s = 0.f;
    if (d < WF_D && n < N_WF) {
        s = b_wf[d];
        #pragma unroll
        for (int z = 0; z < S1_Z; z++)
            s += part[(long long)z * (BB * S1_NPAD * S1T_LD) + idx];
    }
    short h, l; split_bf16(s, h, l);
    oh[idx] = h; ol[idx] = l;
}

// ---- texts -> feat[:, 0:200] split ---------------------------------------
__global__ __launch_bounds__(256)
void texts_split(const float* __restrict__ texts,
                 short* __restrict__ fH, short* __restrict__ fL)
{
    int idx = blockIdx.x * 256 + threadIdx.x;      // exact: 409600 = 1600*256
    int r = idx / 25, ck = (idx % 25) * 8;
    const float* p = texts + (long long)r * TEXT_D + ck;
    float4 t0 = ((const float4*)p)[0];
    float4 t1 = ((const float4*)p)[1];
    float v[8] = {t0.x, t0.y, t0.z, t0.w, t1.x, t1.y, t1.z, t1.w};
    short8 h8, l8;
    #pragma unroll
    for (int q = 0; q < 8; q++) { short h, l; split_bf16(v[q], h, l); h8[q]=h; l8[q]=l; }
    long long o = (long long)r * FEAT_KP + ck;
    *(short8*)&fH[o] = h8;
    *(short8*)&fL[o] = l8;
}

// ---- zero feat pad cols [556,576) ----------------------------------------
__global__ __launch_bounds__(256)
void pad_feat(short* __restrict__ fH, short* __restrict__ fL)
{
    int idx = blockIdx.x * 256 + threadIdx.x;      // exact: 327680 = 1280*256
    int r = idx / 20, j = idx % 20;
    long long o = (long long)r * FEAT_KP + FEAT_K + j;
    fH[o] = 0; fL[o] = 0;
}

// ---- out init: out[r][c] = b2[c] ------------------------------------------
__global__ __launch_bounds__(256)
void init_out(const float* __restrict__ b2, float* __restrict__ out)
{
    int idx = blockIdx.x * 256 + threadIdx.x;      // exact: 32768 = 128*256
    out[idx] = b2[idx & 1];
}

// ---- prep: W1 -> transposed split [256][576] ------------------------------
__global__ __launch_bounds__(256)
void prep_w1t(const float* __restrict__ W1, short* __restrict__ w1th,
              short* __restrict__ w1tl)
{
    int idx = blockIdx.x * 256 + threadIdx.x;      // 72*256 = 18432
    int n = idx / 72, kc = (idx % 72) * 8;
    #pragma unroll
    for (int j = 0; j < 8; j++) {
        int k = kc + j;
        float v = (k < FEAT_K) ? W1[k * FC_H + n] : 0.f;
        short h, l; split_bf16(v, h, l);
        w1th[n * FEAT_KP + k] = h;
        w1tl[n * FEAT_KP + k] = l;
    }
}

// ---- prep: W_wf -> transposed split [128][1024] ---------------------------
__global__ __launch_bounds__(256)
void prep_wwfT(const float* __restrict__ W_wf, short* __restrict__ oh,
               short* __restrict__ ol)
{
    int idx = blockIdx.x * 256 + threadIdx.x;      // exact: 131072 = 512*256
    int n = idx >> 10, k = idx & 1023;
    float v = (n < WF_D && k < WF_LEN) ? W_wf[k * WF_D + n] : 0.f;
    short h, l; split_bf16(v, h, l);
    oh[idx] = h; ol[idx] = l;
}

// ---- prep: W_ts -> transposed split [256][96] -----------------------------
__global__ __launch_bounds__(256)
void prep_wtsT(const float* __restrict__ W_ts, short* __restrict__ oh,
               short* __restrict__ ol)
{
    int idx = blockIdx.x * 256 + threadIdx.x;      // exact: 24576 = 96*256
    int n = idx / S2_KPAD, k = idx % S2_KPAD;
    float v = (k < TS_F) ? W_ts[k * HID + n] : 0.f;
    short h, l; split_bf16(v, h, l);
    oh[idx] = h; ol[idx] = l;
}

// ---- stage 4: h = relu(feat @ W1 + b1), fused head out += h @ W2 ----------
__global__ __launch_bounds__(256)
void gemm_feat_w1_head(const short* __restrict__ featH, const short* __restrict__ featL,
                       const short* __restrict__ w1th, const short* __restrict__ w1tl,
                       const float* __restrict__ b1, const float* __restrict__ W2,
                       float* __restrict__ out)
{
    __shared__ short Ah[128][40], Al[128][40];
    __shared__ short Bh[64][40],  Bl[64][40];

    const int tid  = threadIdx.x;
    const int wv   = tid >> 6, lane = tid & 63;
    const int m16  = lane & 15, quad = lane >> 4, kq = quad * 8;
    const int row0 = blockIdx.y * 128;
    const int col0 = blockIdx.x * 64;

    f32x4 acc[2][4];
    #pragma unroll
    for (int i = 0; i < 2; i++)
        #pragma unroll
        for (int j = 0; j < 4; j++) acc[i][j] = f32x4{0.f, 0.f, 0.f, 0.f};

    const int ar = tid >> 1, akh = (tid & 1) * 16;
    const int bc = tid >> 2, bkh = (tid & 3) * 8;
    const long long abase = (long long)(row0 + ar) * FEAT_KP + akh;
    const long long bbase = (long long)(col0 + bc) * FEAT_KP + bkh;

    for (int k0 = 0; k0 < FEAT_KP; k0 += 32) {
        __syncthreads();
        long long ab = abase + k0;
        *(short8*)&Ah[ar][akh]     = *(const short8*)(featH + ab);
        *(short8*)&Ah[ar][akh + 8] = *(const short8*)(featH + ab + 8);
        *(short8*)&Al[ar][akh]     = *(const short8*)(featL + ab);
        *(short8*)&Al[ar][akh + 8] = *(const short8*)(featL + ab + 8);
        long long bb = bbase + k0;
        *(short8*)&Bh[bc][bkh] = *(const short8*)(w1th + bb);
        *(short8*)&Bl[bc][bkh] = *(const short8*)(w1tl + bb);
        __syncthreads();

        short8 a_h[2], a_l[2];
        #pragma unroll
        for (int i = 0; i < 2; i++) {
            a_h[i] = *(const short8*)&Ah[wv * 32 + i * 16 + m16][kq];
            a_l[i] = *(const short8*)&Al[wv * 32 + i * 16 + m16][kq];
        }
        #pragma unroll
        for (int j = 0; j < 4; j++) {
            short8 b_h = *(const short8*)&Bh[j * 16 + m16][kq];
            short8 b_l = *(const short8*)&Bl[j * 16 + m16][kq];
            #pragma unroll
            for (int i = 0; i < 2; i++) {
                acc[i][j] = __builtin_amdgcn_mfma_f32_16x16x32_bf16(a_h[i], b_h, acc[i][j], 0, 0, 0);
                acc[i][j] = __builtin_amdgcn_mfma_f32_16x16x32_bf16(a_h[i], b_l, acc[i][j], 0, 0, 0);
                acc[i][j] = __builtin_amdgcn_mfma_f32_16x16x32_bf16(a_l[i], b_h, acc[i][j], 0, 0, 0);
            }
        }
    }

    // epilogue: relu + per-row head partials, shuffle-reduce over 16 col lanes
    float o[2][4][2] = {};
    #pragma unroll
    for (int j = 0; j < 4; j++) {
        int c = col0 + j * 16 + m16;
        float bv  = b1[c];
        float w20 = W2[c * 2 + 0];
        float w21 = W2[c * 2 + 1];
        #pragma unroll
        for (int i = 0; i < 2; i++)
            #pragma unroll
            for (int rr = 0; rr < 4; rr++) {
                float v = fmaxf(acc[i][j][rr] + bv, 0.f);
                o[i][rr][0] += v * w20;
                o[i][rr][1] += v * w21;
            }
    }
    #pragma unroll
    for (int i = 0; i < 2; i++)
        #pragma unroll
        for (int rr = 0; rr < 4; rr++) {
            float s0 = o[i][rr][0], s1 = o[i][rr][1];
            #pragma unroll
            for (int mk = 1; mk < 16; mk <<= 1) {
                s0 += __shfl_xor(s0, mk);
                s1 += __shfl_xor(s1, mk);
            }
            if (m16 == 0) {
                int r = row0 + wv * 32 + i * 16 + quad * 4 + rr;
                atomicAdd(&out[r * 2 + 0], s0);
                atomicAdd(&out[r * 2 + 1], s1);
            }
        }
}

extern "C" void kernel_launch(void* const* d_in, const int* in_sizes, int n_in,
                              void* d_out, int out_size, void* d_ws, size_t ws_size,
                              hipStream_t stream)
{
    const float* texts = (const float*)d_in[0];   // (512,32,200)
    const float* ts    = (const float*)d_in[1];   // (512,32,76)
    const float* wf    = (const float*)d_in[2];   // (32,200,1000)
    const float* wwm   = (const float*)d_in[3];   // (32,512,200)
    const float* W_wf  = (const float*)d_in[4];   // (1000,100)
    const float* b_wf  = (const float*)d_in[5];
    const float* W_ts  = (const float*)d_in[6];   // (76,256)
    const float* b_ts  = (const float*)d_in[7];
    const float* W1    = (const float*)d_in[8];   // (556,256)
    const float* b1    = (const float*)d_in[9];
    const float* W2    = (const float*)d_in[10];  // (256,2)
    const float* b2    = (const float*)d_in[11];
    float* out = (float*)d_out;

    // ---- workspace layout (42.6 MB total) ----
    short* w1th  = (short*)d_ws;                  // 256*576 = 147456
    short* w1tl  = w1th  + FC_H * FEAT_KP;
    short* wwfTh = w1tl  + FC_H * FEAT_KP;        // 128*1024 = 131072
    short* wwfTl = wwfTh + S1_NPAD * S1_KPAD;
    short* wtsTh = wwfTl + S1_NPAD * S1_KPAD;     // 256*96 = 24576
    short* wtsTl = wtsTh + HID * S2_KPAD;
    short* wfoTh = wtsTl + HID * S2_KPAD;         // 32*128*224 = 917504
    short* wfoTl = wfoTh + BB * S1_NPAD * S1T_LD;
    short* featH = wfoTl + BB * S1_NPAD * S1T_LD; // 16384*576 = 9437184
    short* featL = featH + (long long)ROWS * FEAT_KP;
    // split-K partials (14.68 MB) alias the feat region — dead before
    // texts_split runs (stream-ordered).
    float* partT = (float*)featH;

    dim3 blk(256);

    // prep (weights are restored before every timed call -> redo each call)
    prep_w1t <<<72,  blk, 0, stream>>>(W1,   w1th,  w1tl);
    prep_wwfT<<<512, blk, 0, stream>>>(W_wf, wwfTh, wwfTl);
    prep_wtsT<<<96,  blk, 0, stream>>>(W_ts, wtsTh, wtsTl);
    init_out <<<128, blk, 0, stream>>>(b2, out);

    // s1: partT[z] = (wf @ W_wf)^T chunks   (M=6400, Npad=128, K=1000)
    gemm_comp<8><<<dim3(1, 100, S1_Z), blk, 0, stream>>>(
        wf, WF_LEN, 0, wwfTh, wwfTl, S1_KPAD, 0,
        nullptr, 1.0f,
        partT, (long long)BB * S1_NPAD * S1T_LD,
        nullptr, nullptr, 0, 0,
        WF_D, WF_LEN, S1_KPS, 3);
    reduce_s1_T<<<3584, blk, 0, stream>>>(partT, b_wf, wfoTh, wfoTl);

    // feat assembly
    texts_split<<<1600, blk, 0, stream>>>(texts, featH, featL);
    pad_feat  <<<1280, blk, 0, stream>>>(featH, featL);

    // s2: feat[:,200:456] = tanh(ts @ W_ts + b_ts)   (M=16384, N=256, K=76)
    gemm_comp<4><<<dim3(4, 256, 1), blk, 0, stream>>>(
        ts, TS_F, 0, wtsTh, wtsTl, S2_KPAD, 0,
        b_ts, 1.0f,
        nullptr, 0,
        featH, featL, TEXT_D, 0,
        HID, TS_F, 0, 1);

    // s3: feat[:,456:556] = (wwm[b] @ wf_out[b]) / 200  (batched, M=512, N=100, K=200)
    gemm_comp<4><<<dim3(2, 8, BB), blk, 0, stream>>>(
        wwm, N_WF, (long long)TT * N_WF,
        wfoTh, wfoTl, S3_KPAD, (long long)S1_NPAD * S1T_LD,
        nullptr, 1.0f / N_WF,
        nullptr, 0,
        featH, featL, TEXT_D + HID, TT,
        WF_D, N_WF, 0, 2);

    // s4 + head: out += (relu(feat @ W1 + b1)) @ W2
    gemm_feat_w1_head<<<dim3(FC_H / 64, ROWS / 128), blk, 0, stream>>>(
        featH, featL, w1th, w1tl, b1, W2, out);
}

// Round 4
// 197.670 us; speedup vs baseline: 2.3315x; 1.0801x over previous
//
#include <hip/hip_runtime.h>
#include <hip/hip_bf16.h>

// Problem constants
#define TT   512
#define BB   32
#define TS_F 76
#define N_WF 200
#define WF_LEN 1000
#define TEXT_D 200
#define WF_D 100
#define HID  256
#define FC_H 256
#define ROWS (TT*BB)              // 16384
#define KTOT 576                  // padded total feat K (556 -> 576)

// stage-1 geometry
#define S1_KPAD 1024
#define S1_NPAD 128
#define S1_Z    4
#define S1_KPS  256
#define S1T_LD  224               // padded n_wf dim of transposed wf_out
#define S2_KPAD 96
#define S3_KPAD 224

// feat2: ts_out cols [0,256) + spread cols [256,356) + zeros [356,376) + pad
#define FEAT2_LD 384

typedef __attribute__((ext_vector_type(8))) short short8;
typedef __attribute__((ext_vector_type(4))) short sshort4;
typedef __attribute__((ext_vector_type(4))) float f32x4;

// RNE bf16 split: v ~= hi + lo (~fp32 combined precision)
__device__ __forceinline__ void split_bf16(float v, short& h, short& l) {
    unsigned u = __builtin_bit_cast(unsigned, v);
    unsigned hr = (u + 0x7FFFu + ((u >> 16) & 1u)) & 0xFFFF0000u;
    h = (short)(hr >> 16);
    float r = v - __builtin_bit_cast(float, hr);
    unsigned u2 = __builtin_bit_cast(unsigned, r);
    unsigned lr = (u2 + 0x7FFFu + ((u2 >> 16) & 1u)) & 0xFFFF0000u;
    l = (short)(lr >> 16);
}

// ====================== prep_all: all weight prep + inits ==================
// blocks [0,72): W1 -> transposed split [256][576]
// blocks [72,584): W_wf -> transposed split [128][1024]
// blocks [584,680): W_ts -> transposed split [256][96]
// blocks [680,808): out[r][c] = b2[c]
// blocks [808,936): zero feat2 cols [356,376) (read by s4 k-chunk 17)
__global__ __launch_bounds__(256)
void prep_all(const float* __restrict__ W1, const float* __restrict__ W_wf,
              const float* __restrict__ W_ts, const float* __restrict__ b2,
              short* __restrict__ w1th, short* __restrict__ w1tl,
              short* __restrict__ wwfTh, short* __restrict__ wwfTl,
              short* __restrict__ wtsTh, short* __restrict__ wtsTl,
              float* __restrict__ out,
              short* __restrict__ featH, short* __restrict__ featL)
{
    const int b = blockIdx.x, tid = threadIdx.x;
    if (b < 72) {                       // W1^T split, 18432 tasks x 8 k
        int idx = b * 256 + tid;
        int n = idx / 72, kc = (idx % 72) * 8;
        #pragma unroll
        for (int j = 0; j < 8; j++) {
            int k = kc + j;
            float v = (k < 556) ? W1[k * FC_H + n] : 0.f;
            short h, l; split_bf16(v, h, l);
            w1th[n * KTOT + k] = h;
            w1tl[n * KTOT + k] = l;
        }
    } else if (b < 584) {               // W_wf^T split, 131072 elems
        int idx = (b - 72) * 256 + tid;
        int n = idx >> 10, k = idx & 1023;
        float v = (n < WF_D && k < WF_LEN) ? W_wf[k * WF_D + n] : 0.f;
        short h, l; split_bf16(v, h, l);
        wwfTh[idx] = h; wwfTl[idx] = l;
    } else if (b < 680) {               // W_ts^T split, 24576 elems
        int idx = (b - 584) * 256 + tid;
        int n = idx / S2_KPAD, k = idx % S2_KPAD;
        float v = (k < TS_F) ? W_ts[k * HID + n] : 0.f;
        short h, l; split_bf16(v, h, l);
        wtsTh[idx] = h; wtsTl[idx] = l;
    } else if (b < 808) {               // out init, 32768 elems
        int idx = (b - 680) * 256 + tid;
        out[idx] = b2[idx & 1];
    } else {                            // feat2 zero strip, 32768 tasks
        int idx = (b - 808) * 256 + tid;
        short* base = (idx >> 14) ? featL : featH;
        int r = idx & 16383;
        sshort4 z = {0, 0, 0, 0};
        #pragma unroll
        for (int q = 0; q < 5; q++)
            *(sshort4*)&base[(long long)r * FEAT2_LD + 356 + q * 4] = z;
    }
}

// ====== s1: partT[z][(b*128+c)*224+n] = (wf @ W_wf)^T k-chunk partials =====
// grid (1, 100, 4); tile 64 rows x 128 cols x 32 k; comp-bf16 (3 MFMA)
__global__ __launch_bounds__(256)
void gemm_s1(const float* __restrict__ wf,
             const short* __restrict__ wwfTh, const short* __restrict__ wwfTl,
             float* __restrict__ partT)
{
    __shared__ short Ah[64][40], Al[64][40];
    __shared__ short Bh[128][40], Bl[128][40];

    const int tid = threadIdx.x;
    const int wv = tid >> 6, lane = tid & 63;
    const int m16 = lane & 15, quad = lane >> 4, kq = quad * 8;
    const int row0 = blockIdx.y * 64;
    const int kb = blockIdx.z * S1_KPS, kend = kb + S1_KPS;
    float* Cb = partT + (long long)blockIdx.z * (BB * S1_NPAD * S1T_LD);

    f32x4 acc[8];
    #pragma unroll
    for (int j = 0; j < 8; j++) acc[j] = f32x4{0.f, 0.f, 0.f, 0.f};

    const int ar = tid >> 2, akc = (tid & 3) * 8;
    const int bc = tid >> 1, bkc = (tid & 1) * 16;

    for (int k0 = kb; k0 < kend; k0 += 32) {
        __syncthreads();
        {   // A: 64x32 fp32 -> split
            int kk = k0 + akc;
            const float* ap = wf + (long long)(row0 + ar) * WF_LEN + kk;
            float v[8];
            if (kk + 8 <= WF_LEN) {
                float4 t0 = ((const float4*)ap)[0];
                float4 t1 = ((const float4*)ap)[1];
                v[0]=t0.x; v[1]=t0.y; v[2]=t0.z; v[3]=t0.w;
                v[4]=t1.x; v[5]=t1.y; v[6]=t1.z; v[7]=t1.w;
            } else {
                #pragma unroll
                for (int q = 0; q < 8; q++) v[q] = (kk + q < WF_LEN) ? ap[q] : 0.f;
            }
            short8 h8, l8;
            #pragma unroll
            for (int q = 0; q < 8; q++) { short h, l; split_bf16(v[q], h, l); h8[q]=h; l8[q]=l; }
            *(short8*)&Ah[ar][akc] = h8;
            *(short8*)&Al[ar][akc] = l8;
        }
        {   // B: 128x32 pre-split
            long long off = (long long)bc * S1_KPAD + k0 + bkc;
            *(short8*)&Bh[bc][bkc]     = *(const short8*)(wwfTh + off);
            *(short8*)&Bh[bc][bkc + 8] = *(const short8*)(wwfTh + off + 8);
            *(short8*)&Bl[bc][bkc]     = *(const short8*)(wwfTl + off);
            *(short8*)&Bl[bc][bkc + 8] = *(const short8*)(wwfTl + off + 8);
        }
        __syncthreads();

        short8 a_h = *(const short8*)&Ah[wv * 16 + m16][kq];
        short8 a_l = *(const short8*)&Al[wv * 16 + m16][kq];
        #pragma unroll
        for (int j = 0; j < 8; j++) {
            short8 b_h = *(const short8*)&Bh[j * 16 + m16][kq];
            short8 b_l = *(const short8*)&Bl[j * 16 + m16][kq];
            acc[j] = __builtin_amdgcn_mfma_f32_16x16x32_bf16(a_h, b_h, acc[j], 0, 0, 0);
            acc[j] = __builtin_amdgcn_mfma_f32_16x16x32_bf16(a_h, b_l, acc[j], 0, 0, 0);
            acc[j] = __builtin_amdgcn_mfma_f32_16x16x32_bf16(a_l, b_h, acc[j], 0, 0, 0);
        }
    }

    // epilogue: transposed partial store (r -> (batch,n), c -> wf_d)
    #pragma unroll
    for (int j = 0; j < 8; j++) {
        int c = j * 16 + m16;
        #pragma unroll
        for (int rr = 0; rr < 4; rr++) {
            int r = row0 + wv * 16 + quad * 4 + rr;
            int bb = r / N_WF, n = r - bb * N_WF;
            Cb[((long long)(bb * S1_NPAD + c)) * S1T_LD + n] = (c < WF_D) ? acc[j][rr] : 0.f;
        }
    }
}

// ---- s1 reduce: wf_outT hi/lo [b][128][224] = sum_z partT + b_wf ----------
__global__ __launch_bounds__(256)
void reduce_s1_T(const float* __restrict__ part, const float* __restrict__ b_wf,
                 short* __restrict__ oh, short* __restrict__ ol)
{
    int idx = blockIdx.x * 256 + threadIdx.x;      // exact: 917504 = 3584*256
    int rem = idx % (S1_NPAD * S1T_LD);
    int d = rem / S1T_LD, n = rem % S1T_LD;
    float s = 0.f;
    if (d < WF_D && n < N_WF) {
        s = b_wf[d];
        #pragma unroll
        for (int z = 0; z < S1_Z; z++)
            s += part[(long long)z * (BB * S1_NPAD * S1T_LD) + idx];
    }
    short h, l; split_bf16(s, h, l);
    oh[idx] = h; ol[idx] = l;
}

// ====== s2+s3 merged: comp-bf16 64x64 tile, epilogue -> feat2 split ========
// blocks [0,1024): s2  feat2[:,0:256)   = tanh(ts @ W_ts + b_ts)
// blocks [1024,1536): s3 feat2[:,256:356) = (wwm[b] @ wf_out[b]) / 200
__global__ __launch_bounds__(256)
void gemm_s23(const float* __restrict__ ts, const float* __restrict__ wwm,
              const short* __restrict__ wtsTh, const short* __restrict__ wtsTl,
              const short* __restrict__ wfoTh, const short* __restrict__ wfoTl,
              const float* __restrict__ b_ts,
              short* __restrict__ featH, short* __restrict__ featL)
{
    __shared__ short Ah[64][40], Al[64][40];
    __shared__ short Bh[64][40], Bl[64][40];

    const int id = blockIdx.x, tid = threadIdx.x;
    const int wv = tid >> 6, lane = tid & 63;
    const int m16 = lane & 15, quad = lane >> 4, kq = quad * 8;

    const float* A; const short *BhB, *BlB; const float* bias;
    int lda, ldbk, K, kend, N, fcol, row0, col0;
    long long frow0; float scale; bool do_tanh;

    if (id < 1024) {            // s2
        int bx = id & 3, by = id >> 2;
        A = ts; lda = TS_F; K = TS_F; kend = S2_KPAD;
        BhB = wtsTh; BlB = wtsTl; ldbk = S2_KPAD;
        bias = b_ts; scale = 1.f; do_tanh = true;
        N = HID; fcol = 0; frow0 = 0;
        row0 = by * 64; col0 = bx * 64;
    } else {                    // s3 (batched)
        int id2 = id - 1024;
        int bz = id2 >> 4, r = id2 & 15, bx = r >> 3, by = r & 7;
        A = wwm + (long long)bz * TT * N_WF; lda = N_WF; K = N_WF; kend = S3_KPAD;
        BhB = wfoTh + (long long)bz * S1_NPAD * S1T_LD;
        BlB = wfoTl + (long long)bz * S1_NPAD * S1T_LD;
        ldbk = S1T_LD;
        bias = nullptr; scale = 1.f / N_WF; do_tanh = false;
        N = WF_D; fcol = HID; frow0 = (long long)bz * TT;
        row0 = by * 64; col0 = bx * 64;
    }

    f32x4 acc[4];
    #pragma unroll
    for (int j = 0; j < 4; j++) acc[j] = f32x4{0.f, 0.f, 0.f, 0.f};

    const int ar = tid >> 2, akc = (tid & 3) * 8;

    for (int k0 = 0; k0 < kend; k0 += 32) {
        __syncthreads();
        {   // A: 64x32 fp32 -> split
            int kk = k0 + akc;
            const float* ap = A + (long long)(row0 + ar) * lda + kk;
            float v[8];
            if (kk + 8 <= K) {
                float4 t0 = ((const float4*)ap)[0];
                float4 t1 = ((const float4*)ap)[1];
                v[0]=t0.x; v[1]=t0.y; v[2]=t0.z; v[3]=t0.w;
                v[4]=t1.x; v[5]=t1.y; v[6]=t1.z; v[7]=t1.w;
            } else {
                #pragma unroll
                for (int q = 0; q < 8; q++) v[q] = (kk + q < K) ? ap[q] : 0.f;
            }
            short8 h8, l8;
            #pragma unroll
            for (int q = 0; q < 8; q++) { short h, l; split_bf16(v[q], h, l); h8[q]=h; l8[q]=l; }
            *(short8*)&Ah[ar][akc] = h8;
            *(short8*)&Al[ar][akc] = l8;
        }
        {   // B: 64x32 pre-split
            long long off = (long long)(col0 + ar) * ldbk + k0 + akc;
            *(short8*)&Bh[ar][akc] = *(const short8*)(BhB + off);
            *(short8*)&Bl[ar][akc] = *(const short8*)(BlB + off);
        }
        __syncthreads();

        short8 a_h = *(const short8*)&Ah[wv * 16 + m16][kq];
        short8 a_l = *(const short8*)&Al[wv * 16 + m16][kq];
        #pragma unroll
        for (int j = 0; j < 4; j++) {
            short8 b_h = *(const short8*)&Bh[j * 16 + m16][kq];
            short8 b_l = *(const short8*)&Bl[j * 16 + m16][kq];
            acc[j] = __builtin_amdgcn_mfma_f32_16x16x32_bf16(a_h, b_h, acc[j], 0, 0, 0);
            acc[j] = __builtin_amdgcn_mfma_f32_16x16x32_bf16(a_h, b_l, acc[j], 0, 0, 0);
            acc[j] = __builtin_amdgcn_mfma_f32_16x16x32_bf16(a_l, b_h, acc[j], 0, 0, 0);
        }
    }

    #pragma unroll
    for (int j = 0; j < 4; j++) {
        int c = col0 + j * 16 + m16;
        if (c >= N) continue;
        #pragma unroll
        for (int rr = 0; rr < 4; rr++) {
            int r = row0 + wv * 16 + quad * 4 + rr;
            float v = acc[j][rr] * scale;
            if (bias) v += bias[c];
            if (do_tanh) v = tanhf(v);
            short h, l; split_bf16(v, h, l);
            long long fo = (frow0 + r) * (long long)FEAT2_LD + fcol + c;
            featH[fo] = h; featL[fo] = l;
        }
    }
}

// ====== s4 + head: out += relu([texts|feat2] @ W1 + b1) @ W2 ===============
// A sources per k: k<200 texts (fp32, split on the fly); k>=200 feat2 (split)
__global__ __launch_bounds__(256)
void gemm_s4_head(const float* __restrict__ texts,
                  const short* __restrict__ featH, const short* __restrict__ featL,
                  const short* __restrict__ w1th, const short* __restrict__ w1tl,
                  const float* __restrict__ b1, const float* __restrict__ W2,
                  float* __restrict__ out)
{
    __shared__ short Ah[128][40], Al[128][40];
    __shared__ short Bh[64][40],  Bl[64][40];

    const int tid = threadIdx.x;
    const int wv = tid >> 6, lane = tid & 63;
    const int m16 = lane & 15, quad = lane >> 4, kq = quad * 8;
    const int row0 = blockIdx.y * 128;
    const int col0 = blockIdx.x * 64;

    f32x4 acc[2][4];
    #pragma unroll
    for (int i = 0; i < 2; i++)
        #pragma unroll
        for (int j = 0; j < 4; j++) acc[i][j] = f32x4{0.f, 0.f, 0.f, 0.f};

    const int ar = tid >> 1, akh = (tid & 1) * 16;
    const int bc = tid >> 2, bkh = (tid & 3) * 8;
    const long long gr = row0 + ar;
    const long long bbase = (long long)(col0 + bc) * KTOT + bkh;

    for (int k0 = 0; k0 < KTOT; k0 += 32) {
        __syncthreads();
        {   // A staging, 16 k's per thread
            int kc = k0 + akh;
            if (kc + 16 <= TEXT_D) {            // pure texts: fp32 + split
                const float* p = texts + gr * TEXT_D + kc;
                float v[16];
                #pragma unroll
                for (int q = 0; q < 4; q++) {
                    float4 t = ((const float4*)p)[q];
                    v[4*q+0]=t.x; v[4*q+1]=t.y; v[4*q+2]=t.z; v[4*q+3]=t.w;
                }
                short8 h0, h1, l0, l1;
                #pragma unroll
                for (int j = 0; j < 8; j++) {
                    short h, l;
                    split_bf16(v[j], h, l);     h0[j]=h; l0[j]=l;
                    split_bf16(v[j+8], h, l);   h1[j]=h; l1[j]=l;
                }
                *(short8*)&Ah[ar][akh]     = h0;
                *(short8*)&Ah[ar][akh + 8] = h1;
                *(short8*)&Al[ar][akh]     = l0;
                *(short8*)&Al[ar][akh + 8] = l1;
            } else if (kc >= TEXT_D) {          // pure feat2: pre-split
                long long o = gr * FEAT2_LD + (kc - TEXT_D);
                *(short8*)&Ah[ar][akh]     = *(const short8*)(featH + o);
                *(short8*)&Ah[ar][akh + 8] = *(const short8*)(featH + o + 8);
                *(short8*)&Al[ar][akh]     = *(const short8*)(featL + o);
                *(short8*)&Al[ar][akh + 8] = *(const short8*)(featL + o + 8);
            } else {                            // mixed chunk (kc == 192)
                #pragma unroll
                for (int j = 0; j < 16; j++) {
                    int k = kc + j;
                    short h, l;
                    if (k < TEXT_D) {
                        split_bf16(texts[gr * TEXT_D + k], h, l);
                    } else {
                        long long o = gr * FEAT2_LD + (k - TEXT_D);
                        h = featH[o]; l = featL[o];
                    }
                    Ah[ar][akh + j] = h;
                    Al[ar][akh + j] = l;
                }
            }
        }
        {   // B staging
            long long bb = bbase + k0;
            *(short8*)&Bh[bc][bkh] = *(const short8*)(w1th + bb);
            *(short8*)&Bl[bc][bkh] = *(const short8*)(w1tl + bb);
        }
        __syncthreads();

        short8 a_h[2], a_l[2];
        #pragma unroll
        for (int i = 0; i < 2; i++) {
            a_h[i] = *(const short8*)&Ah[wv * 32 + i * 16 + m16][kq];
            a_l[i] = *(const short8*)&Al[wv * 32 + i * 16 + m16][kq];
        }
        #pragma unroll
        for (int j = 0; j < 4; j++) {
            short8 b_h = *(const short8*)&Bh[j * 16 + m16][kq];
            short8 b_l = *(const short8*)&Bl[j * 16 + m16][kq];
            #pragma unroll
            for (int i = 0; i < 2; i++) {
                acc[i][j] = __builtin_amdgcn_mfma_f32_16x16x32_bf16(a_h[i], b_h, acc[i][j], 0, 0, 0);
                acc[i][j] = __builtin_amdgcn_mfma_f32_16x16x32_bf16(a_h[i], b_l, acc[i][j], 0, 0, 0);
                acc[i][j] = __builtin_amdgcn_mfma_f32_16x16x32_bf16(a_l[i], b_h, acc[i][j], 0, 0, 0);
            }
        }
    }

    // epilogue: relu + fused head, shuffle-reduce over 16 col lanes
    float o[2][4][2] = {};
    #pragma unroll
    for (int j = 0; j < 4; j++) {
        int c = col0 + j * 16 + m16;
        float bv  = b1[c];
        float w20 = W2[c * 2 + 0];
        float w21 = W2[c * 2 + 1];
        #pragma unroll
        for (int i = 0; i < 2; i++)
            #pragma unroll
            for (int rr = 0; rr < 4; rr++) {
                float v = fmaxf(acc[i][j][rr] + bv, 0.f);
                o[i][rr][0] += v * w20;
                o[i][rr][1] += v * w21;
            }
    }
    #pragma unroll
    for (int i = 0; i < 2; i++)
        #pragma unroll
        for (int rr = 0; rr < 4; rr++) {
            float s0 = o[i][rr][0], s1 = o[i][rr][1];
            #pragma unroll
            for (int mk = 1; mk < 16; mk <<= 1) {
                s0 += __shfl_xor(s0, mk);
                s1 += __shfl_xor(s1, mk);
            }
            if (m16 == 0) {
                int r = row0 + wv * 32 + i * 16 + quad * 4 + rr;
                atomicAdd(&out[r * 2 + 0], s0);
                atomicAdd(&out[r * 2 + 1], s1);
            }
        }
}

extern "C" void kernel_launch(void* const* d_in, const int* in_sizes, int n_in,
                              void* d_out, int out_size, void* d_ws, size_t ws_size,
                              hipStream_t stream)
{
    const float* texts = (const float*)d_in[0];   // (512,32,200)
    const float* ts    = (const float*)d_in[1];   // (512,32,76)
    const float* wf    = (const float*)d_in[2];   // (32,200,1000)
    const float* wwm   = (const float*)d_in[3];   // (32,512,200)
    const float* W_wf  = (const float*)d_in[4];   // (1000,100)
    const float* b_wf  = (const float*)d_in[5];
    const float* W_ts  = (const float*)d_in[6];   // (76,256)
    const float* b_ts  = (const float*)d_in[7];
    const float* W1    = (const float*)d_in[8];   // (556,256)
    const float* b1    = (const float*)d_in[9];
    const float* W2    = (const float*)d_in[10];  // (256,2)
    const float* b2    = (const float*)d_in[11];
    float* out = (float*)d_out;

    // ---- workspace layout (all disjoint, ~44.7 MB) ----
    short* w1th  = (short*)d_ws;                    // 256*576
    short* w1tl  = w1th  + FC_H * KTOT;
    short* wwfTh = w1tl  + FC_H * KTOT;             // 128*1024
    short* wwfTl = wwfTh + S1_NPAD * S1_KPAD;
    short* wtsTh = wwfTl + S1_NPAD * S1_KPAD;       // 256*96
    short* wtsTl = wtsTh + HID * S2_KPAD;
    short* wfoTh = wtsTl + HID * S2_KPAD;           // 32*128*224
    short* wfoTl = wfoTh + BB * S1_NPAD * S1T_LD;
    short* featH = wfoTl + BB * S1_NPAD * S1T_LD;   // 16384*384
    short* featL = featH + (long long)ROWS * FEAT2_LD;
    float* partT = (float*)(featL + (long long)ROWS * FEAT2_LD); // 4*917504 fp32

    dim3 blk(256);

    // 1) all prep + inits (weights restored each call -> redo each call)
    prep_all<<<936, blk, 0, stream>>>(W1, W_wf, W_ts, b2,
                                      w1th, w1tl, wwfTh, wwfTl, wtsTh, wtsTl,
                                      out, featH, featL);

    // 2) s1 split-K partials
    gemm_s1<<<dim3(1, 100, S1_Z), blk, 0, stream>>>(wf, wwfTh, wwfTl, partT);

    // 3) reduce + split -> wf_out^T
    reduce_s1_T<<<3584, blk, 0, stream>>>(partT, b_wf, wfoTh, wfoTl);

    // 4) s2 (tanh proj) + s3 (spread) -> feat2
    gemm_s23<<<1536, blk, 0, stream>>>(ts, wwm, wtsTh, wtsTl, wfoTh, wfoTl,
                                       b_ts, featH, featL);

    // 5) s4 + head
    gemm_s4_head<<<dim3(FC_H / 64, ROWS / 128), blk, 0, stream>>>(
        texts, featH, featL, w1th, w1tl, b1, W2, out);
}

// Round 5
// 187.987 us; speedup vs baseline: 2.4516x; 1.0515x over previous
//
#include <hip/hip_runtime.h>
#include <hip/hip_bf16.h>

// Problem constants
#define TT   512
#define BB   32
#define TS_F 76
#define N_WF 200
#define WF_LEN 1000
#define TEXT_D 200
#define WF_D 100
#define HID  256
#define FC_H 256
#define ROWS (TT*BB)              // 16384
#define KTOT 576                  // padded total feat K (556 -> 576)

// stage-1 geometry
#define S1_KPAD 1024
#define S1_NPAD 128
#define S1_Z    4
#define S1_KPS  256
#define S1T_LD  224               // padded n_wf dim of transposed wf_out
#define S2_KPAD 96
#define S3_KPAD 224

// feat2: ts_out cols [0,256) + spread cols [256,356) + zeros [356,376) + pad
#define FEAT2_LD 384

typedef __attribute__((ext_vector_type(8))) short short8;
typedef __attribute__((ext_vector_type(4))) short sshort4;
typedef __attribute__((ext_vector_type(4))) float f32x4;

// RNE bf16 split: v ~= hi + lo (~fp32 combined precision)
__device__ __forceinline__ void split_bf16(float v, short& h, short& l) {
    unsigned u = __builtin_bit_cast(unsigned, v);
    unsigned hr = (u + 0x7FFFu + ((u >> 16) & 1u)) & 0xFFFF0000u;
    h = (short)(hr >> 16);
    float r = v - __builtin_bit_cast(float, hr);
    unsigned u2 = __builtin_bit_cast(unsigned, r);
    unsigned lr = (u2 + 0x7FFFu + ((u2 >> 16) & 1u)) & 0xFFFF0000u;
    l = (short)(lr >> 16);
}

// ====================== prep_all: all weight prep + inits ==================
__global__ __launch_bounds__(256)
void prep_all(const float* __restrict__ W1, const float* __restrict__ W_wf,
              const float* __restrict__ W_ts, const float* __restrict__ b2,
              short* __restrict__ w1th, short* __restrict__ w1tl,
              short* __restrict__ wwfTh, short* __restrict__ wwfTl,
              short* __restrict__ wtsTh, short* __restrict__ wtsTl,
              float* __restrict__ out,
              short* __restrict__ featH, short* __restrict__ featL)
{
    const int b = blockIdx.x, tid = threadIdx.x;
    if (b < 72) {                       // W1^T split, 18432 tasks x 8 k
        int idx = b * 256 + tid;
        int n = idx / 72, kc = (idx % 72) * 8;
        #pragma unroll
        for (int j = 0; j < 8; j++) {
            int k = kc + j;
            float v = (k < 556) ? W1[k * FC_H + n] : 0.f;
            short h, l; split_bf16(v, h, l);
            w1th[n * KTOT + k] = h;
            w1tl[n * KTOT + k] = l;
        }
    } else if (b < 584) {               // W_wf^T split, 131072 elems
        int idx = (b - 72) * 256 + tid;
        int n = idx >> 10, k = idx & 1023;
        float v = (n < WF_D && k < WF_LEN) ? W_wf[k * WF_D + n] : 0.f;
        short h, l; split_bf16(v, h, l);
        wwfTh[idx] = h; wwfTl[idx] = l;
    } else if (b < 680) {               // W_ts^T split, 24576 elems
        int idx = (b - 584) * 256 + tid;
        int n = idx / S2_KPAD, k = idx % S2_KPAD;
        float v = (k < TS_F) ? W_ts[k * HID + n] : 0.f;
        short h, l; split_bf16(v, h, l);
        wtsTh[idx] = h; wtsTl[idx] = l;
    } else if (b < 808) {               // out init, 32768 elems
        int idx = (b - 680) * 256 + tid;
        out[idx] = b2[idx & 1];
    } else {                            // feat2 zero strip [356,376)
        int idx = (b - 808) * 256 + tid;
        short* base = (idx >> 14) ? featL : featH;
        int r = idx & 16383;
        sshort4 z = {0, 0, 0, 0};
        #pragma unroll
        for (int q = 0; q < 5; q++)
            *(sshort4*)&base[(long long)r * FEAT2_LD + 356 + q * 4] = z;
    }
}

// ====== s1: partT[z][(b*128+c)*224+n] = (wf @ W_wf)^T k-chunk partials =====
__global__ __launch_bounds__(256)
void gemm_s1(const float* __restrict__ wf,
             const short* __restrict__ wwfTh, const short* __restrict__ wwfTl,
             float* __restrict__ partT)
{
    __shared__ short Ah[64][40], Al[64][40];
    __shared__ short Bh[128][40], Bl[128][40];

    const int tid = threadIdx.x;
    const int wv = tid >> 6, lane = tid & 63;
    const int m16 = lane & 15, quad = lane >> 4, kq = quad * 8;
    const int row0 = blockIdx.y * 64;
    const int kb = blockIdx.z * S1_KPS, kend = kb + S1_KPS;
    float* Cb = partT + (long long)blockIdx.z * (BB * S1_NPAD * S1T_LD);

    f32x4 acc[8];
    #pragma unroll
    for (int j = 0; j < 8; j++) acc[j] = f32x4{0.f, 0.f, 0.f, 0.f};

    const int ar = tid >> 2, akc = (tid & 3) * 8;
    const int bc = tid >> 1, bkc = (tid & 1) * 16;

    for (int k0 = kb; k0 < kend; k0 += 32) {
        __syncthreads();
        {   // A: 64x32 fp32 -> split
            int kk = k0 + akc;
            const float* ap = wf + (long long)(row0 + ar) * WF_LEN + kk;
            float v[8];
            if (kk + 8 <= WF_LEN) {
                float4 t0 = ((const float4*)ap)[0];
                float4 t1 = ((const float4*)ap)[1];
                v[0]=t0.x; v[1]=t0.y; v[2]=t0.z; v[3]=t0.w;
                v[4]=t1.x; v[5]=t1.y; v[6]=t1.z; v[7]=t1.w;
            } else {
                #pragma unroll
                for (int q = 0; q < 8; q++) v[q] = (kk + q < WF_LEN) ? ap[q] : 0.f;
            }
            short8 h8, l8;
            #pragma unroll
            for (int q = 0; q < 8; q++) { short h, l; split_bf16(v[q], h, l); h8[q]=h; l8[q]=l; }
            *(short8*)&Ah[ar][akc] = h8;
            *(short8*)&Al[ar][akc] = l8;
        }
        {   // B: 128x32 pre-split
            long long off = (long long)bc * S1_KPAD + k0 + bkc;
            *(short8*)&Bh[bc][bkc]     = *(const short8*)(wwfTh + off);
            *(short8*)&Bh[bc][bkc + 8] = *(const short8*)(wwfTh + off + 8);
            *(short8*)&Bl[bc][bkc]     = *(const short8*)(wwfTl + off);
            *(short8*)&Bl[bc][bkc + 8] = *(const short8*)(wwfTl + off + 8);
        }
        __syncthreads();

        short8 a_h = *(const short8*)&Ah[wv * 16 + m16][kq];
        short8 a_l = *(const short8*)&Al[wv * 16 + m16][kq];
        #pragma unroll
        for (int j = 0; j < 8; j++) {
            short8 b_h = *(const short8*)&Bh[j * 16 + m16][kq];
            short8 b_l = *(const short8*)&Bl[j * 16 + m16][kq];
            acc[j] = __builtin_amdgcn_mfma_f32_16x16x32_bf16(a_h, b_h, acc[j], 0, 0, 0);
            acc[j] = __builtin_amdgcn_mfma_f32_16x16x32_bf16(a_h, b_l, acc[j], 0, 0, 0);
            acc[j] = __builtin_amdgcn_mfma_f32_16x16x32_bf16(a_l, b_h, acc[j], 0, 0, 0);
        }
    }

    #pragma unroll
    for (int j = 0; j < 8; j++) {
        int c = j * 16 + m16;
        #pragma unroll
        for (int rr = 0; rr < 4; rr++) {
            int r = row0 + wv * 16 + quad * 4 + rr;
            int bb = r / N_WF, n = r - bb * N_WF;
            Cb[((long long)(bb * S1_NPAD + c)) * S1T_LD + n] = (c < WF_D) ? acc[j][rr] : 0.f;
        }
    }
}

// ---- s1 reduce: wf_outT hi/lo [b][128][224] = sum_z partT + b_wf ----------
__global__ __launch_bounds__(256)
void reduce_s1_T(const float* __restrict__ part, const float* __restrict__ b_wf,
                 short* __restrict__ oh, short* __restrict__ ol)
{
    int idx = blockIdx.x * 256 + threadIdx.x;      // exact: 917504 = 3584*256
    int rem = idx % (S1_NPAD * S1T_LD);
    int d = rem / S1T_LD, n = rem % S1T_LD;
    float s = 0.f;
    if (d < WF_D && n < N_WF) {
        s = b_wf[d];
        #pragma unroll
        for (int z = 0; z < S1_Z; z++)
            s += part[(long long)z * (BB * S1_NPAD * S1T_LD) + idx];
    }
    short h, l; split_bf16(s, h, l);
    oh[idx] = h; ol[idx] = l;
}

// ====== s2+s3 merged: comp-bf16 64x64 tile, epilogue -> feat2 split ========
__global__ __launch_bounds__(256)
void gemm_s23(const float* __restrict__ ts, const float* __restrict__ wwm,
              const short* __restrict__ wtsTh, const short* __restrict__ wtsTl,
              const short* __restrict__ wfoTh, const short* __restrict__ wfoTl,
              const float* __restrict__ b_ts,
              short* __restrict__ featH, short* __restrict__ featL)
{
    __shared__ short Ah[64][40], Al[64][40];
    __shared__ short Bh[64][40], Bl[64][40];

    const int id = blockIdx.x, tid = threadIdx.x;
    const int wv = tid >> 6, lane = tid & 63;
    const int m16 = lane & 15, quad = lane >> 4, kq = quad * 8;

    const float* A; const short *BhB, *BlB; const float* bias;
    int lda, ldbk, K, kend, N, fcol, row0, col0;
    long long frow0; float scale; bool do_tanh;

    if (id < 1024) {            // s2
        int bx = id & 3, by = id >> 2;
        A = ts; lda = TS_F; K = TS_F; kend = S2_KPAD;
        BhB = wtsTh; BlB = wtsTl; ldbk = S2_KPAD;
        bias = b_ts; scale = 1.f; do_tanh = true;
        N = HID; fcol = 0; frow0 = 0;
        row0 = by * 64; col0 = bx * 64;
    } else {                    // s3 (batched)
        int id2 = id - 1024;
        int bz = id2 >> 4, r = id2 & 15, bx = r >> 3, by = r & 7;
        A = wwm + (long long)bz * TT * N_WF; lda = N_WF; K = N_WF; kend = S3_KPAD;
        BhB = wfoTh + (long long)bz * S1_NPAD * S1T_LD;
        BlB = wfoTl + (long long)bz * S1_NPAD * S1T_LD;
        ldbk = S1T_LD;
        bias = nullptr; scale = 1.f / N_WF; do_tanh = false;
        N = WF_D; fcol = HID; frow0 = (long long)bz * TT;
        row0 = by * 64; col0 = bx * 64;
    }

    f32x4 acc[4];
    #pragma unroll
    for (int j = 0; j < 4; j++) acc[j] = f32x4{0.f, 0.f, 0.f, 0.f};

    const int ar = tid >> 2, akc = (tid & 3) * 8;

    for (int k0 = 0; k0 < kend; k0 += 32) {
        __syncthreads();
        {   // A: 64x32 fp32 -> split
            int kk = k0 + akc;
            const float* ap = A + (long long)(row0 + ar) * lda + kk;
            float v[8];
            if (kk + 8 <= K) {
                float4 t0 = ((const float4*)ap)[0];
                float4 t1 = ((const float4*)ap)[1];
                v[0]=t0.x; v[1]=t0.y; v[2]=t0.z; v[3]=t0.w;
                v[4]=t1.x; v[5]=t1.y; v[6]=t1.z; v[7]=t1.w;
            } else {
                #pragma unroll
                for (int q = 0; q < 8; q++) v[q] = (kk + q < K) ? ap[q] : 0.f;
            }
            short8 h8, l8;
            #pragma unroll
            for (int q = 0; q < 8; q++) { short h, l; split_bf16(v[q], h, l); h8[q]=h; l8[q]=l; }
            *(short8*)&Ah[ar][akc] = h8;
            *(short8*)&Al[ar][akc] = l8;
        }
        {   // B: 64x32 pre-split
            long long off = (long long)(col0 + ar) * ldbk + k0 + akc;
            *(short8*)&Bh[ar][akc] = *(const short8*)(BhB + off);
            *(short8*)&Bl[ar][akc] = *(const short8*)(BlB + off);
        }
        __syncthreads();

        short8 a_h = *(const short8*)&Ah[wv * 16 + m16][kq];
        short8 a_l = *(const short8*)&Al[wv * 16 + m16][kq];
        #pragma unroll
        for (int j = 0; j < 4; j++) {
            short8 b_h = *(const short8*)&Bh[j * 16 + m16][kq];
            short8 b_l = *(const short8*)&Bl[j * 16 + m16][kq];
            acc[j] = __builtin_amdgcn_mfma_f32_16x16x32_bf16(a_h, b_h, acc[j], 0, 0, 0);
            acc[j] = __builtin_amdgcn_mfma_f32_16x16x32_bf16(a_h, b_l, acc[j], 0, 0, 0);
            acc[j] = __builtin_amdgcn_mfma_f32_16x16x32_bf16(a_l, b_h, acc[j], 0, 0, 0);
        }
    }

    #pragma unroll
    for (int j = 0; j < 4; j++) {
        int c = col0 + j * 16 + m16;
        if (c >= N) continue;
        #pragma unroll
        for (int rr = 0; rr < 4; rr++) {
            int r = row0 + wv * 16 + quad * 4 + rr;
            float v = acc[j][rr] * scale;
            if (bias) v += bias[c];
            if (do_tanh) v = tanhf(v);
            short h, l; split_bf16(v, h, l);
            long long fo = (frow0 + r) * (long long)FEAT2_LD + fcol + c;
            featH[fo] = h; featL[fo] = l;
        }
    }
}

// ====== s4 + head: out += relu([texts|feat2] @ W1 + b1) @ W2 ===============
// Full-width: BM=64, BN=256, grid=256 (one block/CU, A fetched exactly once).
// Wave = 64 rows x 64 cols (4x4 tiles). Double-buffered LDS, XOR-swizzled
// k-groups (stride exactly 32 shorts): phys_group = g ^ ((row>>1)&3).
#define S4_NCH 18     // 576/32 K-chunks

__global__ __launch_bounds__(256)
void gemm_s4_head(const float* __restrict__ texts,
                  const short* __restrict__ featH, const short* __restrict__ featL,
                  const short* __restrict__ w1th, const short* __restrict__ w1tl,
                  const float* __restrict__ b1, const float* __restrict__ W2,
                  float* __restrict__ out)
{
    __shared__ short Ah[2][64][32], Al[2][64][32];
    __shared__ short Bh[2][256][32], Bl[2][256][32];

    const int tid = threadIdx.x;
    const int wv = tid >> 6, lane = tid & 63;
    const int m16 = lane & 15, quad = lane >> 4;
    const int row0 = blockIdx.x * 64;

    // fragment-read swizzle: same for all tiles (row ≡ m16 mod 16)
    const int fsw = (quad ^ ((m16 >> 1) & 3)) * 8;

    // staging indices
    const int ar  = tid >> 2;                       // A row 0..63
    const int ag  = tid & 3;                        // A k-group
    const int asw = (ag ^ ((ar >> 1) & 3)) * 8;     // A swizzled offset
    const long long gr = row0 + ar;
    const int bcol = tid;                           // B col 0..255

    f32x4 acc[4][4];
    #pragma unroll
    for (int i = 0; i < 4; i++)
        #pragma unroll
        for (int j = 0; j < 4; j++) acc[i][j] = f32x4{0.f, 0.f, 0.f, 0.f};

    // prefetch registers
    float  va[8];                 // texts path (raw fp32)
    short8 fa_h, fa_l;            // feat2 path (pre-split)
    short8 vb_h[4], vb_l[4];

    auto load_chunk = [&](int c) {
        int kc = c * 32 + ag * 8;
        if (kc + 8 <= TEXT_D) {                 // pure texts (200%8==0 -> never straddles)
            const float4* p = (const float4*)(texts + gr * TEXT_D + kc);
            float4 t0 = p[0], t1 = p[1];
            va[0]=t0.x; va[1]=t0.y; va[2]=t0.z; va[3]=t0.w;
            va[4]=t1.x; va[5]=t1.y; va[6]=t1.z; va[7]=t1.w;
        } else {                                // feat2 (incl. zero strip)
            long long o = gr * FEAT2_LD + (kc - TEXT_D);
            fa_h = *(const short8*)(featH + o);
            fa_l = *(const short8*)(featL + o);
        }
        long long bb = (long long)bcol * KTOT + c * 32;
        #pragma unroll
        for (int g = 0; g < 4; g++) {
            vb_h[g] = *(const short8*)(w1th + bb + g * 8);
            vb_l[g] = *(const short8*)(w1tl + bb + g * 8);
        }
    };

    auto store_chunk = [&](int c, int buf) {
        int kc = c * 32 + ag * 8;
        short8 h8, l8;
        if (kc + 8 <= TEXT_D) {
            #pragma unroll
            for (int q = 0; q < 8; q++) { short h, l; split_bf16(va[q], h, l); h8[q]=h; l8[q]=l; }
        } else { h8 = fa_h; l8 = fa_l; }
        *(short8*)&Ah[buf][ar][asw] = h8;
        *(short8*)&Al[buf][ar][asw] = l8;
        #pragma unroll
        for (int g = 0; g < 4; g++) {
            int s = (g ^ ((bcol >> 1) & 3)) * 8;
            *(short8*)&Bh[buf][bcol][s] = vb_h[g];
            *(short8*)&Bl[buf][bcol][s] = vb_l[g];
        }
    };

    load_chunk(0);
    store_chunk(0, 0);
    __syncthreads();

    for (int c = 0; c < S4_NCH; c++) {
        const int buf = c & 1;
        if (c + 1 < S4_NCH) load_chunk(c + 1);   // global loads in flight over MFMA

        short8 a_h[4], a_l[4];
        #pragma unroll
        for (int ri = 0; ri < 4; ri++) {
            a_h[ri] = *(const short8*)&Ah[buf][ri * 16 + m16][fsw];
            a_l[ri] = *(const short8*)&Al[buf][ri * 16 + m16][fsw];
        }
        #pragma unroll
        for (int ci = 0; ci < 4; ci++) {
            int C = wv * 64 + ci * 16 + m16;
            short8 b_h = *(const short8*)&Bh[buf][C][fsw];
            short8 b_l = *(const short8*)&Bl[buf][C][fsw];
            #pragma unroll
            for (int ri = 0; ri < 4; ri++) {
                acc[ri][ci] = __builtin_amdgcn_mfma_f32_16x16x32_bf16(a_h[ri], b_h, acc[ri][ci], 0, 0, 0);
                acc[ri][ci] = __builtin_amdgcn_mfma_f32_16x16x32_bf16(a_h[ri], b_l, acc[ri][ci], 0, 0, 0);
                acc[ri][ci] = __builtin_amdgcn_mfma_f32_16x16x32_bf16(a_l[ri], b_h, acc[ri][ci], 0, 0, 0);
            }
        }
        if (c + 1 < S4_NCH) {
            store_chunk(c + 1, buf ^ 1);
            __syncthreads();
        }
    }

    // epilogue: relu + fused head; wave owns cols [wv*64, wv*64+64)
    float o0[4][4] = {}, o1[4][4] = {};
    #pragma unroll
    for (int ci = 0; ci < 4; ci++) {
        int C = wv * 64 + ci * 16 + m16;
        float bv  = b1[C];
        float w20 = W2[C * 2 + 0];
        float w21 = W2[C * 2 + 1];
        #pragma unroll
        for (int ri = 0; ri < 4; ri++)
            #pragma unroll
            for (int rr = 0; rr < 4; rr++) {
                float v = fmaxf(acc[ri][ci][rr] + bv, 0.f);
                o0[ri][rr] += v * w20;
                o1[ri][rr] += v * w21;
            }
    }
    #pragma unroll
    for (int ri = 0; ri < 4; ri++)
        #pragma unroll
        for (int rr = 0; rr < 4; rr++) {
            float s0 = o0[ri][rr], s1 = o1[ri][rr];
            #pragma unroll
            for (int mk = 1; mk < 16; mk <<= 1) {
                s0 += __shfl_xor(s0, mk);
                s1 += __shfl_xor(s1, mk);
            }
            if (m16 == 0) {
                int r = row0 + ri * 16 + quad * 4 + rr;
                atomicAdd(&out[r * 2 + 0], s0);
                atomicAdd(&out[r * 2 + 1], s1);
            }
        }
}

extern "C" void kernel_launch(void* const* d_in, const int* in_sizes, int n_in,
                              void* d_out, int out_size, void* d_ws, size_t ws_size,
                              hipStream_t stream)
{
    const float* texts = (const float*)d_in[0];   // (512,32,200)
    const float* ts    = (const float*)d_in[1];   // (512,32,76)
    const float* wf    = (const float*)d_in[2];   // (32,200,1000)
    const float* wwm   = (const float*)d_in[3];   // (32,512,200)
    const float* W_wf  = (const float*)d_in[4];   // (1000,100)
    const float* b_wf  = (const float*)d_in[5];
    const float* W_ts  = (const float*)d_in[6];   // (76,256)
    const float* b_ts  = (const float*)d_in[7];
    const float* W1    = (const float*)d_in[8];   // (556,256)
    const float* b1    = (const float*)d_in[9];
    const float* W2    = (const float*)d_in[10];  // (256,2)
    const float* b2    = (const float*)d_in[11];
    float* out = (float*)d_out;

    // ---- workspace layout (all disjoint, ~44.7 MB) ----
    short* w1th  = (short*)d_ws;                    // 256*576
    short* w1tl  = w1th  + FC_H * KTOT;
    short* wwfTh = w1tl  + FC_H * KTOT;             // 128*1024
    short* wwfTl = wwfTh + S1_NPAD * S1_KPAD;
    short* wtsTh = wwfTl + S1_NPAD * S1_KPAD;       // 256*96
    short* wtsTl = wtsTh + HID * S2_KPAD;
    short* wfoTh = wtsTl + HID * S2_KPAD;           // 32*128*224
    short* wfoTl = wfoTh + BB * S1_NPAD * S1T_LD;
    short* featH = wfoTl + BB * S1_NPAD * S1T_LD;   // 16384*384
    short* featL = featH + (long long)ROWS * FEAT2_LD;
    float* partT = (float*)(featL + (long long)ROWS * FEAT2_LD); // 4*917504 fp32

    dim3 blk(256);

    // 1) all prep + inits
    prep_all<<<936, blk, 0, stream>>>(W1, W_wf, W_ts, b2,
                                      w1th, w1tl, wwfTh, wwfTl, wtsTh, wtsTl,
                                      out, featH, featL);

    // 2) s1 split-K partials
    gemm_s1<<<dim3(1, 100, S1_Z), blk, 0, stream>>>(wf, wwfTh, wwfTl, partT);

    // 3) reduce + split -> wf_out^T
    reduce_s1_T<<<3584, blk, 0, stream>>>(partT, b_wf, wfoTh, wfoTl);

    // 4) s2 (tanh proj) + s3 (spread) -> feat2
    gemm_s23<<<1536, blk, 0, stream>>>(ts, wwm, wtsTh, wtsTl, wfoTh, wfoTl,
                                       b_ts, featH, featL);

    // 5) s4 + head (full-width, double-buffered)
    gemm_s4_head<<<dim3(ROWS / 64), blk, 0, stream>>>(
        texts, featH, featL, w1th, w1tl, b1, W2, out);
}

// Round 6
// 180.404 us; speedup vs baseline: 2.5547x; 1.0420x over previous
//
#include <hip/hip_runtime.h>
#include <hip/hip_bf16.h>

// Problem constants
#define TT   512
#define BB   32
#define TS_F 76
#define N_WF 200
#define WF_LEN 1000
#define TEXT_D 200
#define WF_D 100
#define HID  256
#define FC_H 256
#define ROWS (TT*BB)              // 16384
#define KTOT 576                  // padded total feat K (556 -> 576)

// stage-1 geometry
#define S1_NPAD 128
#define S1_Z    4
#define S1_KPS  256
#define S1T_LD  224               // padded n_wf dim of transposed wf_out
#define S2_KPAD 96
#define S3_KPAD 224

// feat2: ts_out cols [0,256) + spread cols [256,356) + zeros [356,376) + pad
#define FEAT2_LD 384

typedef __attribute__((ext_vector_type(8))) short short8;
typedef __attribute__((ext_vector_type(4))) short sshort4;
typedef __attribute__((ext_vector_type(4))) float f32x4;

// RNE bf16 split: v ~= hi + lo (~fp32 combined precision)
__device__ __forceinline__ void split_bf16(float v, short& h, short& l) {
    unsigned u = __builtin_bit_cast(unsigned, v);
    unsigned hr = (u + 0x7FFFu + ((u >> 16) & 1u)) & 0xFFFF0000u;
    h = (short)(hr >> 16);
    float r = v - __builtin_bit_cast(float, hr);
    unsigned u2 = __builtin_bit_cast(unsigned, r);
    unsigned lr = (u2 + 0x7FFFu + ((u2 >> 16) & 1u)) & 0xFFFF0000u;
    l = (short)(lr >> 16);
}

// ============ K1: s1 partials + s2 feat + W1 prep + inits ==================
// blocks [0,400):      s1  (64x128 tile, split-K z = b/100, W_wf split in-kernel)
// blocks [400,1424):   s2  feat2[:,0:256) = tanh(ts @ W_ts + b_ts), W_ts in-kernel
// blocks [1424,1496):  W1 -> transposed split [256][576]
// blocks [1496,1624):  out init (b2)
// blocks [1624,1752):  feat2 zero strip [356,376)
__global__ __launch_bounds__(256)
void k1_fused(const float* __restrict__ wf, const float* __restrict__ ts,
              const float* __restrict__ W_wf, const float* __restrict__ W_ts,
              const float* __restrict__ W1, const float* __restrict__ b_ts,
              const float* __restrict__ b2,
              float* __restrict__ partT,
              short* __restrict__ featH, short* __restrict__ featL,
              short* __restrict__ w1th, short* __restrict__ w1tl,
              float* __restrict__ out)
{
    __shared__ short smem[15360];   // s1: Ah|Al 64x40, Bh|Bl 128x40; s2: Bh|Bl 64x40

    const int b = blockIdx.x, tid = threadIdx.x;
    const int wv = tid >> 6, lane = tid & 63;
    const int m16 = lane & 15, quad = lane >> 4, kq = quad * 8;

    short* Ah = smem;                 // 64x40
    short* Al = smem + 2560;
    short* Bh = smem + 5120;          // up to 128x40
    short* Bl = smem + 10240;

    if (b < 400) {
        // ---------------- s1 ----------------
        const int by = b % 100, z = b / 100;
        const int row0 = by * 64;
        const int kb = z * S1_KPS, kend = kb + S1_KPS;
        float* Cb = partT + (long long)z * (BB * S1_NPAD * S1T_LD);

        f32x4 acc[8];
        #pragma unroll
        for (int j = 0; j < 8; j++) acc[j] = f32x4{0.f, 0.f, 0.f, 0.f};

        const int ar = tid >> 2, akc = (tid & 3) * 8;

        for (int k0 = kb; k0 < kend; k0 += 32) {
            __syncthreads();
            {   // A: 64x32 fp32 -> split
                int kk = k0 + akc;
                const float* ap = wf + (long long)(row0 + ar) * WF_LEN + kk;
                float v[8];
                if (kk + 8 <= WF_LEN) {
                    float4 t0 = ((const float4*)ap)[0];
                    float4 t1 = ((const float4*)ap)[1];
                    v[0]=t0.x; v[1]=t0.y; v[2]=t0.z; v[3]=t0.w;
                    v[4]=t1.x; v[5]=t1.y; v[6]=t1.z; v[7]=t1.w;
                } else {
                    #pragma unroll
                    for (int q = 0; q < 8; q++) v[q] = (kk + q < WF_LEN) ? ap[q] : 0.f;
                }
                short8 h8, l8;
                #pragma unroll
                for (int q = 0; q < 8; q++) { short h, l; split_bf16(v[q], h, l); h8[q]=h; l8[q]=l; }
                *(short8*)&Ah[ar * 40 + akc] = h8;
                *(short8*)&Al[ar * 40 + akc] = l8;
            }
            {   // B: 128x32 = W_wf^T chunk, split in-kernel (W_wf is L2-hot)
                #pragma unroll
                for (int i = 0; i < 2; i++) {
                    int t = tid * 2 + i;
                    int c = t >> 2, kg = (t & 3) * 8;
                    float v[8];
                    #pragma unroll
                    for (int q = 0; q < 8; q++) {
                        int k = k0 + kg + q;
                        v[q] = (k < WF_LEN && c < WF_D) ? W_wf[k * WF_D + c] : 0.f;
                    }
                    short8 h8, l8;
                    #pragma unroll
                    for (int q = 0; q < 8; q++) { short h, l; split_bf16(v[q], h, l); h8[q]=h; l8[q]=l; }
                    *(short8*)&Bh[c * 40 + kg] = h8;
                    *(short8*)&Bl[c * 40 + kg] = l8;
                }
            }
            __syncthreads();

            short8 a_h = *(const short8*)&Ah[(wv * 16 + m16) * 40 + kq];
            short8 a_l = *(const short8*)&Al[(wv * 16 + m16) * 40 + kq];
            #pragma unroll
            for (int j = 0; j < 8; j++) {
                short8 b_h = *(const short8*)&Bh[(j * 16 + m16) * 40 + kq];
                short8 b_l = *(const short8*)&Bl[(j * 16 + m16) * 40 + kq];
                acc[j] = __builtin_amdgcn_mfma_f32_16x16x32_bf16(a_h, b_h, acc[j], 0, 0, 0);
                acc[j] = __builtin_amdgcn_mfma_f32_16x16x32_bf16(a_h, b_l, acc[j], 0, 0, 0);
                acc[j] = __builtin_amdgcn_mfma_f32_16x16x32_bf16(a_l, b_h, acc[j], 0, 0, 0);
            }
        }

        #pragma unroll
        for (int j = 0; j < 8; j++) {
            int c = j * 16 + m16;
            #pragma unroll
            for (int rr = 0; rr < 4; rr++) {
                int r = row0 + wv * 16 + quad * 4 + rr;
                int bb = r / N_WF, n = r - bb * N_WF;
                Cb[((long long)(bb * S1_NPAD + c)) * S1T_LD + n] = (c < WF_D) ? acc[j][rr] : 0.f;
            }
        }
    } else if (b < 1424) {
        // ---------------- s2 ----------------
        const int id2 = b - 400;
        const int bx = id2 & 3, by = id2 >> 2;
        const int row0 = by * 64, col0 = bx * 64;

        f32x4 acc[4];
        #pragma unroll
        for (int j = 0; j < 4; j++) acc[j] = f32x4{0.f, 0.f, 0.f, 0.f};

        const int ar = tid >> 2, akc = (tid & 3) * 8;

        for (int k0 = 0; k0 < S2_KPAD; k0 += 32) {
            __syncthreads();
            {   // A: 64x32 from ts
                int kk = k0 + akc;
                const float* ap = ts + (long long)(row0 + ar) * TS_F + kk;
                float v[8];
                if (kk + 8 <= TS_F) {
                    float4 t0 = ((const float4*)ap)[0];
                    float4 t1 = ((const float4*)ap)[1];
                    v[0]=t0.x; v[1]=t0.y; v[2]=t0.z; v[3]=t0.w;
                    v[4]=t1.x; v[5]=t1.y; v[6]=t1.z; v[7]=t1.w;
                } else {
                    #pragma unroll
                    for (int q = 0; q < 8; q++) v[q] = (kk + q < TS_F) ? ap[q] : 0.f;
                }
                short8 h8, l8;
                #pragma unroll
                for (int q = 0; q < 8; q++) { short h, l; split_bf16(v[q], h, l); h8[q]=h; l8[q]=l; }
                *(short8*)&Ah[ar * 40 + akc] = h8;
                *(short8*)&Al[ar * 40 + akc] = l8;
            }
            {   // B: 64x32 = W_ts^T chunk, split in-kernel (W_ts is tiny/L2-hot)
                int c = tid >> 2, kg = (tid & 3) * 8;
                float v[8];
                #pragma unroll
                for (int q = 0; q < 8; q++) {
                    int k = k0 + kg + q;
                    v[q] = (k < TS_F) ? W_ts[k * HID + col0 + c] : 0.f;
                }
                short8 h8, l8;
                #pragma unroll
                for (int q = 0; q < 8; q++) { short h, l; split_bf16(v[q], h, l); h8[q]=h; l8[q]=l; }
                *(short8*)&Bh[c * 40 + kg] = h8;
                *(short8*)&Bl[c * 40 + kg] = l8;
            }
            __syncthreads();

            short8 a_h = *(const short8*)&Ah[(wv * 16 + m16) * 40 + kq];
            short8 a_l = *(const short8*)&Al[(wv * 16 + m16) * 40 + kq];
            #pragma unroll
            for (int j = 0; j < 4; j++) {
                short8 b_h = *(const short8*)&Bh[(j * 16 + m16) * 40 + kq];
                short8 b_l = *(const short8*)&Bl[(j * 16 + m16) * 40 + kq];
                acc[j] = __builtin_amdgcn_mfma_f32_16x16x32_bf16(a_h, b_h, acc[j], 0, 0, 0);
                acc[j] = __builtin_amdgcn_mfma_f32_16x16x32_bf16(a_h, b_l, acc[j], 0, 0, 0);
                acc[j] = __builtin_amdgcn_mfma_f32_16x16x32_bf16(a_l, b_h, acc[j], 0, 0, 0);
            }
        }

        #pragma unroll
        for (int j = 0; j < 4; j++) {
            int c = col0 + j * 16 + m16;
            #pragma unroll
            for (int rr = 0; rr < 4; rr++) {
                int r = row0 + wv * 16 + quad * 4 + rr;
                float v = tanhf(acc[j][rr] + b_ts[c]);
                short h, l; split_bf16(v, h, l);
                long long fo = (long long)r * FEAT2_LD + c;
                featH[fo] = h; featL[fo] = l;
            }
        }
    } else if (b < 1496) {              // W1^T split
        int idx = (b - 1424) * 256 + tid;
        int n = idx / 72, kc = (idx % 72) * 8;
        #pragma unroll
        for (int j = 0; j < 8; j++) {
            int k = kc + j;
            float v = (k < 556) ? W1[k * FC_H + n] : 0.f;
            short h, l; split_bf16(v, h, l);
            w1th[n * KTOT + k] = h;
            w1tl[n * KTOT + k] = l;
        }
    } else if (b < 1624) {              // out init
        int idx = (b - 1496) * 256 + tid;
        out[idx] = b2[idx & 1];
    } else {                            // feat2 zero strip [356,376)
        int idx = (b - 1624) * 256 + tid;
        short* base = (idx >> 14) ? featL : featH;
        int r = idx & 16383;
        sshort4 zz = {0, 0, 0, 0};
        #pragma unroll
        for (int q = 0; q < 5; q++)
            *(sshort4*)&base[(long long)r * FEAT2_LD + 356 + q * 4] = zz;
    }
}

// ---- K2: wf_outT hi/lo [b][128][224] = sum_z partT + b_wf -----------------
__global__ __launch_bounds__(256)
void k2_reduce(const float* __restrict__ part, const float* __restrict__ b_wf,
               short* __restrict__ oh, short* __restrict__ ol)
{
    int idx = blockIdx.x * 256 + threadIdx.x;      // exact: 917504 = 3584*256
    int rem = idx % (S1_NPAD * S1T_LD);
    int d = rem / S1T_LD, n = rem % S1T_LD;
    float s = 0.f;
    if (d < WF_D && n < N_WF) {
        s = b_wf[d];
        #pragma unroll
        for (int z = 0; z < S1_Z; z++)
            s += part[(long long)z * (BB * S1_NPAD * S1T_LD) + idx];
    }
    short h, l; split_bf16(s, h, l);
    oh[idx] = h; ol[idx] = l;
}

// ---- K3: s3 feat2[:,256:356) = (wwm[b] @ wf_out[b]) / 200 -----------------
__global__ __launch_bounds__(256)
void k3_s3(const float* __restrict__ wwm,
           const short* __restrict__ wfoTh, const short* __restrict__ wfoTl,
           short* __restrict__ featH, short* __restrict__ featL)
{
    __shared__ short Ah[64][40], Al[64][40];
    __shared__ short Bh[64][40], Bl[64][40];

    const int id = blockIdx.x, tid = threadIdx.x;
    const int wv = tid >> 6, lane = tid & 63;
    const int m16 = lane & 15, quad = lane >> 4, kq = quad * 8;

    const int bz = id >> 4, r4 = id & 15, bx = r4 >> 3, by = r4 & 7;
    const float* A = wwm + (long long)bz * TT * N_WF;
    const short* BhB = wfoTh + (long long)bz * S1_NPAD * S1T_LD;
    const short* BlB = wfoTl + (long long)bz * S1_NPAD * S1T_LD;
    const long long frow0 = (long long)bz * TT;
    const int row0 = by * 64, col0 = bx * 64;

    f32x4 acc[4];
    #pragma unroll
    for (int j = 0; j < 4; j++) acc[j] = f32x4{0.f, 0.f, 0.f, 0.f};

    const int ar = tid >> 2, akc = (tid & 3) * 8;

    for (int k0 = 0; k0 < S3_KPAD; k0 += 32) {
        __syncthreads();
        {   // A: 64x32 from wwm
            int kk = k0 + akc;
            const float* ap = A + (long long)(row0 + ar) * N_WF + kk;
            float v[8];
            if (kk + 8 <= N_WF) {
                float4 t0 = ((const float4*)ap)[0];
                float4 t1 = ((const float4*)ap)[1];
                v[0]=t0.x; v[1]=t0.y; v[2]=t0.z; v[3]=t0.w;
                v[4]=t1.x; v[5]=t1.y; v[6]=t1.z; v[7]=t1.w;
            } else {
                #pragma unroll
                for (int q = 0; q < 8; q++) v[q] = (kk + q < N_WF) ? ap[q] : 0.f;
            }
            short8 h8, l8;
            #pragma unroll
            for (int q = 0; q < 8; q++) { short h, l; split_bf16(v[q], h, l); h8[q]=h; l8[q]=l; }
            *(short8*)&Ah[ar][akc] = h8;
            *(short8*)&Al[ar][akc] = l8;
        }
        {   // B: 64x32 pre-split wf_outT
            long long off = (long long)(col0 + ar) * S1T_LD + k0 + akc;
            *(short8*)&Bh[ar][akc] = *(const short8*)(BhB + off);
            *(short8*)&Bl[ar][akc] = *(const short8*)(BlB + off);
        }
        __syncthreads();

        short8 a_h = *(const short8*)&Ah[wv * 16 + m16][kq];
        short8 a_l = *(const short8*)&Al[wv * 16 + m16][kq];
        #pragma unroll
        for (int j = 0; j < 4; j++) {
            short8 b_h = *(const short8*)&Bh[j * 16 + m16][kq];
            short8 b_l = *(const short8*)&Bl[j * 16 + m16][kq];
            acc[j] = __builtin_amdgcn_mfma_f32_16x16x32_bf16(a_h, b_h, acc[j], 0, 0, 0);
            acc[j] = __builtin_amdgcn_mfma_f32_16x16x32_bf16(a_h, b_l, acc[j], 0, 0, 0);
            acc[j] = __builtin_amdgcn_mfma_f32_16x16x32_bf16(a_l, b_h, acc[j], 0, 0, 0);
        }
    }

    #pragma unroll
    for (int j = 0; j < 4; j++) {
        int c = col0 + j * 16 + m16;
        if (c >= WF_D) continue;
        #pragma unroll
        for (int rr = 0; rr < 4; rr++) {
            int r = row0 + wv * 16 + quad * 4 + rr;
            float v = acc[j][rr] * (1.0f / N_WF);
            short h, l; split_bf16(v, h, l);
            long long fo = (frow0 + r) * (long long)FEAT2_LD + HID + c;
            featH[fo] = h; featL[fo] = l;
        }
    }
}

// ====== K4: s4 + head, 512 threads (8 waves), wave = 64 rows x 32 cols =====
#define S4_NCH 18     // 576/32 K-chunks

__global__ __launch_bounds__(512)
void k4_s4head(const float* __restrict__ texts,
               const short* __restrict__ featH, const short* __restrict__ featL,
               const short* __restrict__ w1th, const short* __restrict__ w1tl,
               const float* __restrict__ b1, const float* __restrict__ W2,
               float* __restrict__ out)
{
    __shared__ short Ah[2][64][32], Al[2][64][32];
    __shared__ short Bh[2][256][32], Bl[2][256][32];

    const int tid = threadIdx.x;
    const int wv = tid >> 6, lane = tid & 63;
    const int m16 = lane & 15, quad = lane >> 4;
    const int row0 = blockIdx.x * 64;

    const int fsw = (quad ^ ((m16 >> 1) & 3)) * 8;

    // A staging (tid < 256): one (h,l) short8 pair
    const int ar  = tid >> 2;
    const int ag  = tid & 3;
    const int asw = (ag ^ ((ar >> 1) & 3)) * 8;
    const long long gr = row0 + ar;

    f32x4 acc[4][2];
    #pragma unroll
    for (int i = 0; i < 4; i++)
        #pragma unroll
        for (int j = 0; j < 2; j++) acc[i][j] = f32x4{0.f, 0.f, 0.f, 0.f};

    float  va[8];
    short8 fa_h, fa_l;
    short8 vb_h[2], vb_l[2];

    auto load_chunk = [&](int c) {
        if (tid < 256) {
            int kc = c * 32 + ag * 8;
            if (kc + 8 <= TEXT_D) {             // texts (200%8==0: never straddles)
                const float4* p = (const float4*)(texts + gr * TEXT_D + kc);
                float4 t0 = p[0], t1 = p[1];
                va[0]=t0.x; va[1]=t0.y; va[2]=t0.z; va[3]=t0.w;
                va[4]=t1.x; va[5]=t1.y; va[6]=t1.z; va[7]=t1.w;
            } else {
                long long o = gr * FEAT2_LD + (kc - TEXT_D);
                fa_h = *(const short8*)(featH + o);
                fa_l = *(const short8*)(featL + o);
            }
        }
        #pragma unroll
        for (int i = 0; i < 2; i++) {
            int t = tid * 2 + i;
            int bcol = t >> 2, bg = t & 3;
            long long bb = (long long)bcol * KTOT + c * 32 + bg * 8;
            vb_h[i] = *(const short8*)(w1th + bb);
            vb_l[i] = *(const short8*)(w1tl + bb);
        }
    };

    auto store_chunk = [&](int c, int buf) {
        if (tid < 256) {
            int kc = c * 32 + ag * 8;
            short8 h8, l8;
            if (kc + 8 <= TEXT_D) {
                #pragma unroll
                for (int q = 0; q < 8; q++) { short h, l; split_bf16(va[q], h, l); h8[q]=h; l8[q]=l; }
            } else { h8 = fa_h; l8 = fa_l; }
            *(short8*)&Ah[buf][ar][asw] = h8;
            *(short8*)&Al[buf][ar][asw] = l8;
        }
        #pragma unroll
        for (int i = 0; i < 2; i++) {
            int t = tid * 2 + i;
            int bcol = t >> 2, bg = t & 3;
            int s = (bg ^ ((bcol >> 1) & 3)) * 8;
            *(short8*)&Bh[buf][bcol][s] = vb_h[i];
            *(short8*)&Bl[buf][bcol][s] = vb_l[i];
        }
    };

    load_chunk(0);
    store_chunk(0, 0);
    __syncthreads();

    for (int c = 0; c < S4_NCH; c++) {
        const int buf = c & 1;
        if (c + 1 < S4_NCH) load_chunk(c + 1);

        short8 a_h[4], a_l[4];
        #pragma unroll
        for (int ri = 0; ri < 4; ri++) {
            a_h[ri] = *(const short8*)&Ah[buf][ri * 16 + m16][fsw];
            a_l[ri] = *(const short8*)&Al[buf][ri * 16 + m16][fsw];
        }
        #pragma unroll
        for (int ci = 0; ci < 2; ci++) {
            int C = wv * 32 + ci * 16 + m16;
            short8 b_h = *(const short8*)&Bh[buf][C][fsw];
            short8 b_l = *(const short8*)&Bl[buf][C][fsw];
            #pragma unroll
            for (int ri = 0; ri < 4; ri++) {
                acc[ri][ci] = __builtin_amdgcn_mfma_f32_16x16x32_bf16(a_h[ri], b_h, acc[ri][ci], 0, 0, 0);
                acc[ri][ci] = __builtin_amdgcn_mfma_f32_16x16x32_bf16(a_h[ri], b_l, acc[ri][ci], 0, 0, 0);
                acc[ri][ci] = __builtin_amdgcn_mfma_f32_16x16x32_bf16(a_l[ri], b_h, acc[ri][ci], 0, 0, 0);
            }
        }
        if (c + 1 < S4_NCH) {
            store_chunk(c + 1, buf ^ 1);
            __syncthreads();
        }
    }

    // epilogue: relu + fused head over this wave's 32 cols
    float o0[4][4] = {}, o1[4][4] = {};
    #pragma unroll
    for (int ci = 0; ci < 2; ci++) {
        int C = wv * 32 + ci * 16 + m16;
        float bv  = b1[C];
        float w20 = W2[C * 2 + 0];
        float w21 = W2[C * 2 + 1];
        #pragma unroll
        for (int ri = 0; ri < 4; ri++)
            #pragma unroll
            for (int rr = 0; rr < 4; rr++) {
                float v = fmaxf(acc[ri][ci][rr] + bv, 0.f);
                o0[ri][rr] += v * w20;
                o1[ri][rr] += v * w21;
            }
    }
    #pragma unroll
    for (int ri = 0; ri < 4; ri++)
        #pragma unroll
        for (int rr = 0; rr < 4; rr++) {
            float s0 = o0[ri][rr], s1 = o1[ri][rr];
            #pragma unroll
            for (int mk = 1; mk < 16; mk <<= 1) {
                s0 += __shfl_xor(s0, mk);
                s1 += __shfl_xor(s1, mk);
            }
            if (m16 == 0) {
                int r = row0 + ri * 16 + quad * 4 + rr;
                atomicAdd(&out[r * 2 + 0], s0);
                atomicAdd(&out[r * 2 + 1], s1);
            }
        }
}

extern "C" void kernel_launch(void* const* d_in, const int* in_sizes, int n_in,
                              void* d_out, int out_size, void* d_ws, size_t ws_size,
                              hipStream_t stream)
{
    const float* texts = (const float*)d_in[0];   // (512,32,200)
    const float* ts    = (const float*)d_in[1];   // (512,32,76)
    const float* wf    = (const float*)d_in[2];   // (32,200,1000)
    const float* wwm   = (const float*)d_in[3];   // (32,512,200)
    const float* W_wf  = (const float*)d_in[4];   // (1000,100)
    const float* b_wf  = (const float*)d_in[5];
    const float* W_ts  = (const float*)d_in[6];   // (76,256)
    const float* b_ts  = (const float*)d_in[7];
    const float* W1    = (const float*)d_in[8];   // (556,256)
    const float* b1    = (const float*)d_in[9];
    const float* W2    = (const float*)d_in[10];  // (256,2)
    const float* b2    = (const float*)d_in[11];
    float* out = (float*)d_out;

    // ---- workspace layout (all disjoint, ~41 MB) ----
    short* w1th  = (short*)d_ws;                    // 256*576
    short* w1tl  = w1th  + FC_H * KTOT;
    short* wfoTh = w1tl  + FC_H * KTOT;             // 32*128*224
    short* wfoTl = wfoTh + BB * S1_NPAD * S1T_LD;
    short* featH = wfoTl + BB * S1_NPAD * S1T_LD;   // 16384*384
    short* featL = featH + (long long)ROWS * FEAT2_LD;
    float* partT = (float*)(featL + (long long)ROWS * FEAT2_LD); // 4*917504 fp32

    // 1) s1 partials + s2 feat + W1 prep + out init + feat2 zero
    k1_fused<<<1752, 256, 0, stream>>>(wf, ts, W_wf, W_ts, W1, b_ts, b2,
                                       partT, featH, featL, w1th, w1tl, out);

    // 2) reduce + split -> wf_out^T
    k2_reduce<<<3584, 256, 0, stream>>>(partT, b_wf, wfoTh, wfoTl);

    // 3) s3 -> feat2 spread cols
    k3_s3<<<512, 256, 0, stream>>>(wwm, wfoTh, wfoTl, featH, featL);

    // 4) s4 + head (8 waves/block)
    k4_s4head<<<ROWS / 64, 512, 0, stream>>>(texts, featH, featL,
                                             w1th, w1tl, b1, W2, out);
}